// Round 1
// baseline (1029.827 us; speedup 1.0000x reference)
//
#include <hip/hip_runtime.h>

#define BT 16384
#define NF 39
#define FD 26000

typedef unsigned short u16;
typedef unsigned int u32;
typedef short bf16x8 __attribute__((ext_vector_type(8)));
typedef float f32x4 __attribute__((ext_vector_type(4)));

__device__ __forceinline__ float bf2f(u16 h) {
  union { u32 u; float f; } v; v.u = ((u32)h) << 16; return v.f;
}
__device__ __forceinline__ u16 f2bf(float f) {
  union { float f; u32 u; } v; v.f = f;
  u32 r = v.u + 0x7fffu + ((v.u >> 16) & 1u);
  return (u16)(r >> 16);
}
// async global->LDS, 16B/lane; LDS dest = wave-uniform base + lane*16.
__device__ __forceinline__ void gld16(const u16* g, u16* l) {
  __builtin_amdgcn_global_load_lds(
      (const __attribute__((address_space(1))) void*)g,
      (__attribute__((address_space(3))) void*)l, 16, 0, 0);
}

// ---------------------------------------------------------------------------
// prep: z=0..2 transpose+cast W1/W2/W3 (f32 [K][400] -> bf16 [400+][Kpad],
// K-pad zero, rows 400..447 zero);  z=3 cast Wt -> bf16 (row-major).
// ---------------------------------------------------------------------------
__global__ __launch_bounds__(256) void k_prep(
    const float* __restrict__ W1, u16* __restrict__ W1T,
    const float* __restrict__ W2, u16* __restrict__ W2T,
    const float* __restrict__ W3, u16* __restrict__ W3T,
    const float* __restrict__ Wt, u16* __restrict__ Wtb)
{
  int z = blockIdx.z;
  if (z == 3) {
    int idx = (blockIdx.y * 14 + blockIdx.x) * 256 + threadIdx.x;
    if (idx < NF * 4096) Wtb[idx] = f2bf(Wt[idx]);
    return;
  }
  const float* in = (z == 0) ? W1 : (z == 1) ? W2 : W3;
  u16* outp = (z == 0) ? W1T : (z == 1) ? W2T : W3T;
  int K = (z == 0) ? 2496 : 400;
  int Kpad = (z == 0) ? 2496 : 448;
  int r0 = blockIdx.y * 32, c0 = blockIdx.x * 32;
  if (r0 >= Kpad) return;
  __shared__ u16 t[32][33];
  int tx = threadIdx.x & 31, ty = threadIdx.x >> 5;
  for (int i = ty; i < 32; i += 8) {
    int r = r0 + i, c = c0 + tx;
    t[i][tx] = (r < K && c < 400) ? f2bf(in[(long)r * 400 + c]) : (u16)0;
  }
  __syncthreads();
  int r = r0 + tx;
  if (r < Kpad)
    for (int i = ty; i < 32; i += 8)
      outp[(long)(c0 + i) * Kpad + r] = t[tx][i];
}

// ---------------------------------------------------------------------------
// k_embed_mlp1: fused gather+gate -> {FM (trans MFMA), first-order term,
// layer-1 GEMM}.  h0 is never materialized: per field f, the 64-wide K-slice
// of W1T is staged to LDS (double-buffered, XOR chunk swizzle) and 56 MFMAs
// per wave accumulate the 64x448 layer-1 output in registers across all 39
// fields.  256 blocks x 64 rows = BT; 1 block/CU (LDS 148.9KB), 1 wave/SIMD
// (launch_bounds(256,1) -> 512-VGPR budget).
// Writes h1 = relu(BN(h0@W1+b1)) [16384][448] bf16 (pad cols zeroed) + base.
// ---------------------------------------------------------------------------
__global__ __launch_bounds__(256, 1) void k_embed_mlp1(
    const int* __restrict__ x, const float* __restrict__ emb,
    const float* __restrict__ lin_table, const float* __restrict__ lin_bias,
    const float* __restrict__ sparse_var, const u16* __restrict__ Wtb,
    const float* __restrict__ bt, const u16* __restrict__ W1T,
    const float* __restrict__ b1, const float* __restrict__ g1,
    const float* __restrict__ be1, u16* __restrict__ h1,
    float* __restrict__ base)
{
  __shared__ u16                s_x[64 * NF];        //   4992 B
  __shared__ float              s_sv[NF * 64];       //   9984 B
  __shared__ __align__(16) u16  s_emb[2][64 * 72];   //  18432 B
  __shared__ __align__(16) u16  s_w1[2][448 * 64];   // 114688 B (chunk-swizzled)
  __shared__ float              s_fm[128];           //    512 B
  __shared__ float              s_lin[64];           //    256 B -> 148864 B

  const int tid = threadIdx.x;
  const int b0 = blockIdx.x * 64;

  for (int i = tid; i < 64 * NF; i += 256) s_x[i] = (u16)x[b0 * NF + i];
  for (int i = tid; i < NF * 64; i += 256) {
    float v = sparse_var[i];
    float s = 1.0f / (1.0f + __expf(-15.0f * v));
    s_sv[i] = (s > 0.001f) ? s : 0.0f;
  }
  __syncthreads();

  const int wave = tid >> 6, lane = tid & 63;
  const int quad = lane >> 4, c16 = lane & 15;
  const int mh = wave >> 1, jh = wave & 1;           // FM: m-half / col-half
  const int g_row = tid >> 2, g_c16 = (tid & 3) * 16;
  // W1 staging: lane -> (row_rel = lane>>3, phys chunk = lane&7); fetch
  // logical chunk (lane&7)^row_rel so phys p at row r holds logical p^(r&7).
  const int srow = lane >> 3;
  const u16* gW = W1T + ((lane & 7) ^ srow) * 8;

  f32x4 acc[7][4];                                    // [nt][m] layer-1
  #pragma unroll
  for (int nt = 0; nt < 7; ++nt)
    #pragma unroll
    for (int m = 0; m < 4; ++m) acc[nt][m] = {0.f, 0.f, 0.f, 0.f};
  float accS[2][2][4];                                // [mloc][j][r] FM sums
  float q[2][4];                                      // [mloc][r] FM squares
  #pragma unroll
  for (int ml = 0; ml < 2; ++ml)
    #pragma unroll
    for (int r = 0; r < 4; ++r) {
      accS[ml][0][r] = 0.f; accS[ml][1][r] = 0.f; q[ml][r] = 0.f;
    }

  // ---- prologue: stage W1 slice f=0, gather+gate field 0
  #pragma unroll
  for (int it = 0; it < 14; ++it) {
    int s = wave * 14 + it;
    gld16(gW + (long)(s * 8 + srow) * 2496, &s_w1[0][s * 512]);
  }
  {
    long gi = (long)((int)s_x[g_row * NF + 0]);
    const float* src = emb + gi * 64 + g_c16;
    float4 e0 = *(const float4*)(src);
    float4 e1 = *(const float4*)(src + 4);
    float4 e2 = *(const float4*)(src + 8);
    float4 e3 = *(const float4*)(src + 12);
    const float* svp = &s_sv[g_c16];
    float4 s0 = *(const float4*)(svp);
    float4 s1 = *(const float4*)(svp + 4);
    float4 s2 = *(const float4*)(svp + 8);
    float4 s3 = *(const float4*)(svp + 12);
    union { uint4 v; u16 h[8]; } p0, p1;
    p0.h[0] = f2bf(e0.x * s0.x); p0.h[1] = f2bf(e0.y * s0.y);
    p0.h[2] = f2bf(e0.z * s0.z); p0.h[3] = f2bf(e0.w * s0.w);
    p0.h[4] = f2bf(e1.x * s1.x); p0.h[5] = f2bf(e1.y * s1.y);
    p0.h[6] = f2bf(e1.z * s1.z); p0.h[7] = f2bf(e1.w * s1.w);
    p1.h[0] = f2bf(e2.x * s2.x); p1.h[1] = f2bf(e2.y * s2.y);
    p1.h[2] = f2bf(e2.z * s2.z); p1.h[3] = f2bf(e2.w * s2.w);
    p1.h[4] = f2bf(e3.x * s3.x); p1.h[5] = f2bf(e3.y * s3.y);
    p1.h[6] = f2bf(e3.z * s3.z); p1.h[7] = f2bf(e3.w * s3.w);
    *(uint4*)&s_emb[0][g_row * 72 + g_c16] = p0.v;
    *(uint4*)&s_emb[0][g_row * 72 + g_c16 + 8] = p1.v;
  }
  __syncthreads();

  for (int f = 0; f < NF; ++f) {
    const int cur = f & 1, nxt = cur ^ 1;
    const bool more = (f + 1) < NF;

    // async-stage next W1 slice (consumed next iter; drained by the barrier)
    if (more) {
      #pragma unroll
      for (int it = 0; it < 14; ++it) {
        int s = wave * 14 + it;
        gld16(gW + (long)(s * 8 + srow) * 2496 + (f + 1) * 64,
              &s_w1[nxt][s * 512]);
      }
    }

    // FM B-frags + bias direct from L2-resident Wtb/bt (consumed at the end,
    // so their latency hides under the 56 layer-1 MFMAs)
    bf16x8 bwt[2][2];
    float btv[2];
    #pragma unroll
    for (int j = 0; j < 2; ++j) {
      int o = (jh * 2 + j) * 16 + c16;
      bwt[j][0] = *(const bf16x8*)(Wtb + f * 4096 + o * 64 + quad * 8);
      bwt[j][1] = *(const bf16x8*)(Wtb + f * 4096 + o * 64 + 32 + quad * 8);
      btv[j] = bt[f * 64 + o];
    }

    // gather prefetch for field f+1 (consumed at the bottom)
    float4 e0, e1, e2, e3;
    if (more) {
      long gi = (long)((int)s_x[g_row * NF + f + 1] + (f + 1) * FD);
      const float* src = emb + gi * 64 + g_c16;
      e0 = *(const float4*)(src);
      e1 = *(const float4*)(src + 4);
      e2 = *(const float4*)(src + 8);
      e3 = *(const float4*)(src + 12);
    }

    // A-frags (shared by layer-1 and FM)
    bf16x8 a[4][2];
    #pragma unroll
    for (int m = 0; m < 4; ++m) {
      #pragma unroll
      for (int ks = 0; ks < 2; ++ks)
        a[m][ks] = *(const bf16x8*)
            &s_emb[cur][(m * 16 + c16) * 72 + ks * 32 + quad * 8];
    }

    // layer-1 GEMM: wave owns cols [wave*112, wave*112+112)
    #pragma unroll
    for (int nt = 0; nt < 7; ++nt) {
      int n = wave * 112 + nt * 16 + c16;
      #pragma unroll
      for (int ks = 0; ks < 2; ++ks) {
        bf16x8 b = *(const bf16x8*)
            &s_w1[cur][n * 64 + (((ks * 4 + quad) ^ (c16 & 7)) * 8)];
        #pragma unroll
        for (int m = 0; m < 4; ++m)
          acc[nt][m] = __builtin_amdgcn_mfma_f32_16x16x32_bf16(
              a[m][ks], b, acc[nt][m], 0, 0, 0);
      }
    }

    // FM trans MFMA + stats
    #pragma unroll
    for (int mloc = 0; mloc < 2; ++mloc) {
      int m = mh * 2 + mloc;
      #pragma unroll
      for (int j = 0; j < 2; ++j) {
        f32x4 t = {0.f, 0.f, 0.f, 0.f};
        t = __builtin_amdgcn_mfma_f32_16x16x32_bf16(a[m][0], bwt[j][0], t, 0, 0, 0);
        t = __builtin_amdgcn_mfma_f32_16x16x32_bf16(a[m][1], bwt[j][1], t, 0, 0, 0);
        #pragma unroll
        for (int r = 0; r < 4; ++r) {
          float tv = t[r] + btv[j];
          accS[mloc][j][r] += tv;
          q[mloc][r] += tv * tv;
        }
      }
    }

    // pack gathered field f+1 into s_emb[nxt]
    if (more) {
      const float* svp = &s_sv[(f + 1) * 64 + g_c16];
      float4 s0 = *(const float4*)(svp);
      float4 s1 = *(const float4*)(svp + 4);
      float4 s2 = *(const float4*)(svp + 8);
      float4 s3 = *(const float4*)(svp + 12);
      union { uint4 v; u16 h[8]; } p0, p1;
      p0.h[0] = f2bf(e0.x * s0.x); p0.h[1] = f2bf(e0.y * s0.y);
      p0.h[2] = f2bf(e0.z * s0.z); p0.h[3] = f2bf(e0.w * s0.w);
      p0.h[4] = f2bf(e1.x * s1.x); p0.h[5] = f2bf(e1.y * s1.y);
      p0.h[6] = f2bf(e1.z * s1.z); p0.h[7] = f2bf(e1.w * s1.w);
      p1.h[0] = f2bf(e2.x * s2.x); p1.h[1] = f2bf(e2.y * s2.y);
      p1.h[2] = f2bf(e2.z * s2.z); p1.h[3] = f2bf(e2.w * s2.w);
      p1.h[4] = f2bf(e3.x * s3.x); p1.h[5] = f2bf(e3.y * s3.y);
      p1.h[6] = f2bf(e3.z * s3.z); p1.h[7] = f2bf(e3.w * s3.w);
      *(uint4*)&s_emb[nxt][g_row * 72 + g_c16] = p0.v;
      *(uint4*)&s_emb[nxt][g_row * 72 + g_c16 + 8] = p1.v;
    }
    __syncthreads();
  }

  // ---- epilogue 1: h1 = relu((acc + b1) * BN_INV*g1 + be1), pad cols zero
  const float BN_INV = 0.9999950000374997f;
  #pragma unroll
  for (int nt = 0; nt < 7; ++nt) {
    int col = wave * 112 + nt * 16 + c16;
    if (col < 400) {
      float bb = b1[col];
      float sc = BN_INV * g1[col];
      float bv = be1[col];
      #pragma unroll
      for (int m = 0; m < 4; ++m) {
        #pragma unroll
        for (int r = 0; r < 4; ++r) {
          int row = b0 + m * 16 + quad * 4 + r;
          float y = (acc[nt][m][r] + bb) * sc + bv;
          y = fmaxf(y, 0.f);
          h1[(long)row * 448 + col] = f2bf(y);
        }
      }
    } else {
      #pragma unroll
      for (int m = 0; m < 4; ++m)
        #pragma unroll
        for (int r = 0; r < 4; ++r)
          h1[(long)(b0 + m * 16 + quad * 4 + r) * 448 + col] = 0;
    }
  }

  // ---- epilogue 2: FM reduce across the 16 col-lanes of each col-half
  #pragma unroll
  for (int mloc = 0; mloc < 2; ++mloc) {
    #pragma unroll
    for (int r = 0; r < 4; ++r) {
      float v = accS[mloc][0][r] * accS[mloc][0][r]
              + accS[mloc][1][r] * accS[mloc][1][r] - q[mloc][r];
      v += __shfl_xor(v, 1, 64);
      v += __shfl_xor(v, 2, 64);
      v += __shfl_xor(v, 4, 64);
      v += __shfl_xor(v, 8, 64);
      if (c16 == 0)
        s_fm[jh * 64 + (mh * 2 + mloc) * 16 + quad * 4 + r] = v;
    }
  }
  // ---- epilogue 3: first-order term, 4 threads per row
  {
    int row = tid >> 2, fi = tid & 3;
    float lv = 0.f;
    for (int f = fi; f < NF; f += 4)
      lv += lin_table[(int)s_x[row * NF + f] + f * FD];
    lv += __shfl_xor(lv, 1, 64);
    lv += __shfl_xor(lv, 2, 64);
    if (fi == 0) s_lin[row] = lv;
  }
  __syncthreads();
  if (tid < 64)
    base[b0 + tid] = s_lin[tid] + lin_bias[0]
                   + 0.5f * (s_fm[tid] + s_fm[64 + tid]);
}

// ---------------------------------------------------------------------------
// MLP GEMM (layers 2,3), m97-style: global_load_lds(16B) staging, XOR-swizzled
// unpadded LDS, tile 128x80xBK64. C = relu((A@B + b)*BN_INV*g + be). K=kit*64.
// ---------------------------------------------------------------------------
__global__ __launch_bounds__(256) void k_gemm(
    const u16* __restrict__ A, int lda, const u16* __restrict__ Bt, int ldb,
    int kit, const float* __restrict__ bias, const float* __restrict__ g,
    const float* __restrict__ be, u16* __restrict__ C, int ldc)
{
  __shared__ __align__(16) u16 sA[128 * 64];
  __shared__ __align__(16) u16 sB[80 * 64];

  const int tid = threadIdx.x;
  int bid = blockIdx.x;
  int xcd = bid & 7;
  int j = bid >> 3;
  const int m0 = (xcd * 16 + j / 5) * 128;
  const int n0 = (j % 5) * 80;

  const int wave = tid >> 6, lane = tid & 63;
  const int quad = lane >> 4, c16 = lane & 15;

  const int srow = lane >> 3;
  const int sclog = (lane & 7) ^ (srow & 7);
  const u16* gA = A + (long)m0 * lda + sclog * 8;
  const u16* gB = Bt + (long)n0 * ldb + sclog * 8;

  f32x4 acc[2][5];
  #pragma unroll
  for (int mtt = 0; mtt < 2; ++mtt)
    #pragma unroll
    for (int nt = 0; nt < 5; ++nt) acc[mtt][nt] = {0.f, 0.f, 0.f, 0.f};

  for (int kk = 0; kk < kit; ++kk) {
    const int k0 = kk * 64;
    #pragma unroll
    for (int it = 0; it < 4; ++it) {
      int s = wave * 4 + it;
      gld16(gA + (long)(s * 8 + srow) * lda + k0, &sA[s * 512]);
    }
    gld16(gB + (long)(wave * 8 + srow) * ldb + k0, &sB[wave * 512]);
    gld16(gB + (long)((wave + 4) * 8 + srow) * ldb + k0, &sB[(wave + 4) * 512]);
    if (wave < 2)
      gld16(gB + (long)((wave + 8) * 8 + srow) * ldb + k0, &sB[(wave + 8) * 512]);
    __syncthreads();

    #pragma unroll
    for (int ks = 0; ks < 2; ++ks) {
      const int co = ((ks * 4 + quad) ^ (c16 & 7)) * 8;
      bf16x8 a0 = *(const bf16x8*)&sA[(wave * 32 + c16) * 64 + co];
      bf16x8 a1 = *(const bf16x8*)&sA[(wave * 32 + 16 + c16) * 64 + co];
      #pragma unroll
      for (int nt = 0; nt < 5; ++nt) {
        bf16x8 b = *(const bf16x8*)&sB[(nt * 16 + c16) * 64 + co];
        acc[0][nt] = __builtin_amdgcn_mfma_f32_16x16x32_bf16(a0, b, acc[0][nt], 0, 0, 0);
        acc[1][nt] = __builtin_amdgcn_mfma_f32_16x16x32_bf16(a1, b, acc[1][nt], 0, 0, 0);
      }
    }
    __syncthreads();
  }

  const float BN_INV = 0.9999950000374997f;
  #pragma unroll
  for (int nt = 0; nt < 5; ++nt) {
    int col = n0 + nt * 16 + c16;
    float bb = bias[col];
    float sc = BN_INV * g[col];
    float bv = be[col];
    #pragma unroll
    for (int mtt = 0; mtt < 2; ++mtt) {
      #pragma unroll
      for (int r = 0; r < 4; ++r) {
        int row = m0 + wave * 32 + mtt * 16 + quad * 4 + r;
        float y = (acc[mtt][nt][r] + bb) * sc + bv;
        y = fmaxf(y, 0.f);
        C[(long)row * ldc + col] = f2bf(y);
      }
    }
  }
  if (ldc > 400 && n0 == 320) {
    int npad = ldc - 400;
    for (int s = tid; s < 128 * npad; s += 256) {
      int rr = s / npad, cc = s % npad;
      C[(long)(m0 + rr) * ldc + 400 + cc] = 0;
    }
  }
}

// ---------------------------------------------------------------------------
// Final: out[b] = sigmoid(base[b] + h3[b,:].Wout + bout). One wave per row.
// ---------------------------------------------------------------------------
__global__ __launch_bounds__(256) void k_final(
    const u16* __restrict__ h3, const float* __restrict__ Wout,
    const float* __restrict__ bout, const float* __restrict__ base,
    float* __restrict__ out)
{
  int wave = threadIdx.x >> 6, lane = threadIdx.x & 63;
  int b = blockIdx.x * 4 + wave;
  float s = 0.f;
  for (int jj = lane; jj < 400; jj += 64)
    s += bf2f(h3[(long)b * 448 + jj]) * Wout[jj];
  #pragma unroll
  for (int m = 32; m >= 1; m >>= 1) s += __shfl_xor(s, m, 64);
  if (lane == 0) {
    float z = s + base[b] + bout[0];
    out[b] = 1.0f / (1.0f + __expf(-z));
  }
}

extern "C" void kernel_launch(void* const* d_in, const int* in_sizes, int n_in,
                              void* d_out, int out_size, void* d_ws, size_t ws_size,
                              hipStream_t stream)
{
  const int*   x         = (const int*)d_in[0];
  const float* emb       = (const float*)d_in[1];
  const float* lin_table = (const float*)d_in[2];
  const float* lin_bias  = (const float*)d_in[3];
  const float* svar      = (const float*)d_in[4];
  const float* Wt        = (const float*)d_in[5];
  const float* bt        = (const float*)d_in[6];
  const float* W1  = (const float*)d_in[7];
  const float* b1  = (const float*)d_in[8];
  const float* g1  = (const float*)d_in[9];
  const float* be1 = (const float*)d_in[10];
  const float* W2  = (const float*)d_in[11];
  const float* b2  = (const float*)d_in[12];
  const float* g2  = (const float*)d_in[13];
  const float* be2 = (const float*)d_in[14];
  const float* W3  = (const float*)d_in[15];
  const float* b3  = (const float*)d_in[16];
  const float* g3  = (const float*)d_in[17];
  const float* be3 = (const float*)d_in[18];
  const float* Wo  = (const float*)d_in[19];
  const float* bo  = (const float*)d_in[20];

  char* ws = (char*)d_ws;
  size_t off = 0;
  u16* h1 = (u16*)(ws + off);     off += (size_t)BT * 448 * 2;
  u16* h2 = (u16*)(ws + off);     off += (size_t)BT * 448 * 2;
  u16* h3 = (u16*)(ws + off);     off += (size_t)BT * 448 * 2;
  float* base = (float*)(ws + off); off += (size_t)BT * 4;
  u16* W1T = (u16*)(ws + off);    off += (size_t)448 * 2496 * 2;
  u16* W2T = (u16*)(ws + off);    off += (size_t)448 * 448 * 2;
  u16* W3T = (u16*)(ws + off);    off += (size_t)448 * 448 * 2;
  u16* Wtb = (u16*)(ws + off);    off += (size_t)NF * 4096 * 2;
  (void)ws_size; (void)in_sizes; (void)n_in; (void)out_size;

  k_prep<<<dim3(14, 78, 4), 256, 0, stream>>>(W1, W1T, W2, W2T, W3, W3T, Wt, Wtb);
  k_embed_mlp1<<<256, 256, 0, stream>>>(x, emb, lin_table, lin_bias, svar, Wtb,
                                        bt, W1T, b1, g1, be1, h1, base);
  k_gemm<<<640, 256, 0, stream>>>(h1, 448, W2T, 448, 7, b2, g2, be2, h2, 448);
  k_gemm<<<640, 256, 0, stream>>>(h2, 448, W3T, 448, 7, b3, g3, be3, h3, 448);
  k_final<<<4096, 256, 0, stream>>>(h3, Wo, bo, base, (float*)d_out);
}

// Round 4
// 533.864 us; speedup vs baseline: 1.9290x; 1.9290x over previous
//
#include <hip/hip_runtime.h>

#define BT 16384
#define NF 39
#define FD 26000

typedef unsigned short u16;
typedef unsigned int u32;
typedef short bf16x8 __attribute__((ext_vector_type(8)));
typedef float f32x4 __attribute__((ext_vector_type(4)));

__device__ __forceinline__ float bf2f(u16 h) {
  union { u32 u; float f; } v; v.u = ((u32)h) << 16; return v.f;
}
__device__ __forceinline__ u16 f2bf(float f) {
  union { float f; u32 u; } v; v.f = f;
  u32 r = v.u + 0x7fffu + ((v.u >> 16) & 1u);
  return (u16)(r >> 16);
}
// async global->LDS, 16B/lane; LDS dest = wave-uniform base + lane*16.
__device__ __forceinline__ void gld16(const u16* g, u16* l) {
  __builtin_amdgcn_global_load_lds(
      (const __attribute__((address_space(1))) void*)g,
      (__attribute__((address_space(3))) void*)l, 16, 0, 0);
}

// ---------------------------------------------------------------------------
// prep: z=0..2 transpose+cast W1/W2/W3 (f32 [K][400] -> bf16 [400+][Kpad],
// K-pad zero, rows 400..447 zero);  z=3 cast Wt -> bf16 (row-major).
// ---------------------------------------------------------------------------
__global__ __launch_bounds__(256) void k_prep(
    const float* __restrict__ W1, u16* __restrict__ W1T,
    const float* __restrict__ W2, u16* __restrict__ W2T,
    const float* __restrict__ W3, u16* __restrict__ W3T,
    const float* __restrict__ Wt, u16* __restrict__ Wtb)
{
  int z = blockIdx.z;
  if (z == 3) {
    int idx = (blockIdx.y * 14 + blockIdx.x) * 256 + threadIdx.x;
    if (idx < NF * 4096) Wtb[idx] = f2bf(Wt[idx]);
    return;
  }
  const float* in = (z == 0) ? W1 : (z == 1) ? W2 : W3;
  u16* outp = (z == 0) ? W1T : (z == 1) ? W2T : W3T;
  int K = (z == 0) ? 2496 : 400;
  int Kpad = (z == 0) ? 2496 : 448;
  int r0 = blockIdx.y * 32, c0 = blockIdx.x * 32;
  if (r0 >= Kpad) return;
  __shared__ u16 t[32][33];
  int tx = threadIdx.x & 31, ty = threadIdx.x >> 5;
  for (int i = ty; i < 32; i += 8) {
    int r = r0 + i, c = c0 + tx;
    t[i][tx] = (r < K && c < 400) ? f2bf(in[(long)r * 400 + c]) : (u16)0;
  }
  __syncthreads();
  int r = r0 + tx;
  if (r < Kpad)
    for (int i = ty; i < 32; i += 8)
      outp[(long)(c0 + i) * Kpad + r] = t[tx][i];
}

// ---------------------------------------------------------------------------
// k_embed_mlp1 v2b: round-0 k_embed skeleton (512 blocks x 32 rows, 1 barrier
// per field, gather prefetched one field ahead) + fused layer-1 GEMM.
// h0 is never materialized.  W1 is NOT LDS-staged (same L2 bytes either way):
// each wave reads its layer-1 B-frags directly from L2-resident W1T
// ([448][2496] bf16, output-major).  Per wave: cols [wave*112,+112),
// acc[7][2] f32x4 persistent across the 39 fields; FM trans col-quarter per
// wave + first-order term as in round-0.  LDS ~32KB.
// NOTE: plain launch_bounds(256) (no min-wave bound) — matches every kernel
// that has run successfully; natural VGPR ~140-170 still gives 2 waves/SIMD.
// Writes h1 = relu(BN(h0@W1+b1)) [16384][448] bf16 (pad cols zero) + base.
// ---------------------------------------------------------------------------
__global__ __launch_bounds__(256) void k_embed_mlp1(
    const int* __restrict__ x, const float* __restrict__ emb,
    const float* __restrict__ lin_table, const float* __restrict__ lin_bias,
    const float* __restrict__ sparse_var, const u16* __restrict__ Wtb,
    const float* __restrict__ bt, const u16* __restrict__ W1T,
    const float* __restrict__ b1, const float* __restrict__ g1,
    const float* __restrict__ be1, u16* __restrict__ h1,
    float* __restrict__ base)
{
  __shared__ u16                s_x[32 * NF];        // 2496 B
  __shared__ float              s_sv[NF * 64];       // 9984 B
  __shared__ float              s_bt[NF * 64];       // 9984 B
  __shared__ __align__(16) u16  s_emb[2][32 * 72];   // 9216 B (stride 72)
  __shared__ float              s_fm[4][32];         //  512 B
  __shared__ float              s_lin[32];           //  128 B  -> ~32.3 KB

  const int tid = threadIdx.x;
  const int b0 = blockIdx.x * 32;

  for (int i = tid; i < 32 * NF; i += 256) s_x[i] = (u16)x[b0 * NF + i];
  for (int i = tid; i < NF * 64; i += 256) {
    float v = sparse_var[i];
    float s = 1.0f / (1.0f + __expf(-15.0f * v));
    s_sv[i] = (s > 0.001f) ? s : 0.0f;
    s_bt[i] = bt[i];
  }
  __syncthreads();

  const int wave = tid >> 6, lane = tid & 63;
  const int quad = lane >> 4, c16 = lane & 15;
  const int g_row = tid >> 3, g_c8 = (tid & 7) * 8;

  // per-lane operand bases (elements).  Layer-1 B-frag for (nt,ks):
  //   W1T[(wave*112 + nt*16 + c16) * 2496 + f*64 + ks*32 + quad*8]
  // FM B-frag for ks: Wtb[f*4096 + (wave*16 + c16)*64 + ks*32 + quad*8]
  const u16* w1p = W1T + (long)(wave * 112 + c16) * 2496 + quad * 8;
  const u16* wtp = Wtb + (long)(wave * 16 + c16) * 64 + quad * 8;

  f32x4 acc[7][2];                                    // [nt][m] layer-1
  #pragma unroll
  for (int nt = 0; nt < 7; ++nt) {
    acc[nt][0] = {0.f, 0.f, 0.f, 0.f};
    acc[nt][1] = {0.f, 0.f, 0.f, 0.f};
  }
  float accS[2][4], q[2][4];                          // FM per m-group
  #pragma unroll
  for (int m = 0; m < 2; ++m)
    #pragma unroll
    for (int r = 0; r < 4; ++r) { accS[m][r] = 0.f; q[m][r] = 0.f; }

  // ---- prologue: gather+gate field 0 into s_emb[0]
  {
    long gi = (long)((int)s_x[g_row * NF + 0]);
    float4 e0 = *(const float4*)&emb[gi * 64 + g_c8];
    float4 e1 = *(const float4*)&emb[gi * 64 + g_c8 + 4];
    union { uint4 v; u16 h[8]; } p;
    p.h[0] = f2bf(e0.x * s_sv[g_c8 + 0]);
    p.h[1] = f2bf(e0.y * s_sv[g_c8 + 1]);
    p.h[2] = f2bf(e0.z * s_sv[g_c8 + 2]);
    p.h[3] = f2bf(e0.w * s_sv[g_c8 + 3]);
    p.h[4] = f2bf(e1.x * s_sv[g_c8 + 4]);
    p.h[5] = f2bf(e1.y * s_sv[g_c8 + 5]);
    p.h[6] = f2bf(e1.z * s_sv[g_c8 + 6]);
    p.h[7] = f2bf(e1.w * s_sv[g_c8 + 7]);
    *(uint4*)&s_emb[0][g_row * 72 + g_c8] = p.v;
  }
  __syncthreads();

  for (int f = 0; f < NF; ++f) {
    const int cur = f & 1, nxt = cur ^ 1;
    const bool more = (f + 1) < NF;

    // FM B-frags + bias (L2-resident Wtb, 312 KB)
    bf16x8 bwt0 = *(const bf16x8*)(wtp + f * 4096);
    bf16x8 bwt1 = *(const bf16x8*)(wtp + f * 4096 + 32);
    float btv = s_bt[f * 64 + wave * 16 + c16];

    // gather prefetch for field f+1 (consumed by the pack at the bottom)
    float4 e0, e1;
    if (more) {
      long gi = (long)((int)s_x[g_row * NF + f + 1] + (f + 1) * FD);
      e0 = *(const float4*)&emb[gi * 64 + g_c8];
      e1 = *(const float4*)&emb[gi * 64 + g_c8 + 4];
    }

    // A-frags (shared by layer-1 and FM)
    bf16x8 a[2][2];
    #pragma unroll
    for (int m = 0; m < 2; ++m)
      #pragma unroll
      for (int ks = 0; ks < 2; ++ks)
        a[m][ks] = *(const bf16x8*)
            &s_emb[cur][(m * 16 + c16) * 72 + ks * 32 + quad * 8];

    // layer-1 GEMM: B-frags straight from L2 (57 KB/block/field, no staging)
    const u16* w1f = w1p + f * 64;
    #pragma unroll
    for (int nt = 0; nt < 7; ++nt) {
      #pragma unroll
      for (int ks = 0; ks < 2; ++ks) {
        bf16x8 b = *(const bf16x8*)(w1f + (long)nt * 16 * 2496 + ks * 32);
        acc[nt][0] = __builtin_amdgcn_mfma_f32_16x16x32_bf16(
            a[0][ks], b, acc[nt][0], 0, 0, 0);
        acc[nt][1] = __builtin_amdgcn_mfma_f32_16x16x32_bf16(
            a[1][ks], b, acc[nt][1], 0, 0, 0);
      }
    }

    // FM trans MFMA + stats (this wave's 16-col quarter, both row groups)
    #pragma unroll
    for (int m = 0; m < 2; ++m) {
      f32x4 t = {0.f, 0.f, 0.f, 0.f};
      t = __builtin_amdgcn_mfma_f32_16x16x32_bf16(a[m][0], bwt0, t, 0, 0, 0);
      t = __builtin_amdgcn_mfma_f32_16x16x32_bf16(a[m][1], bwt1, t, 0, 0, 0);
      #pragma unroll
      for (int r = 0; r < 4; ++r) {
        float tv = t[r] + btv;
        accS[m][r] += tv;
        q[m][r] += tv * tv;
      }
    }

    // pack gathered field f+1 into s_emb[nxt]
    if (more) {
      const float* sv = &s_sv[(f + 1) * 64 + g_c8];
      union { uint4 v; u16 h[8]; } p;
      p.h[0] = f2bf(e0.x * sv[0]);
      p.h[1] = f2bf(e0.y * sv[1]);
      p.h[2] = f2bf(e0.z * sv[2]);
      p.h[3] = f2bf(e0.w * sv[3]);
      p.h[4] = f2bf(e1.x * sv[4]);
      p.h[5] = f2bf(e1.y * sv[5]);
      p.h[6] = f2bf(e1.z * sv[6]);
      p.h[7] = f2bf(e1.w * sv[7]);
      *(uint4*)&s_emb[nxt][g_row * 72 + g_c8] = p.v;
    }
    __syncthreads();
  }

  // ---- epilogue 1: h1 = relu((acc + b1) * BN_INV*g1 + be1), pad cols zero
  const float BN_INV = 0.9999950000374997f;
  #pragma unroll
  for (int nt = 0; nt < 7; ++nt) {
    int col = wave * 112 + nt * 16 + c16;
    if (col < 400) {
      float bb = b1[col];
      float sc = BN_INV * g1[col];
      float bv = be1[col];
      #pragma unroll
      for (int m = 0; m < 2; ++m) {
        #pragma unroll
        for (int r = 0; r < 4; ++r) {
          int row = b0 + m * 16 + quad * 4 + r;
          float y = (acc[nt][m][r] + bb) * sc + bv;
          y = fmaxf(y, 0.f);
          h1[(long)row * 448 + col] = f2bf(y);
        }
      }
    } else {
      #pragma unroll
      for (int m = 0; m < 2; ++m)
        #pragma unroll
        for (int r = 0; r < 4; ++r)
          h1[(long)(b0 + m * 16 + quad * 4 + r) * 448 + col] = 0;
    }
  }

  // ---- epilogue 2: FM partial (this wave's col quarter) -> s_fm[wave][row]
  #pragma unroll
  for (int m = 0; m < 2; ++m) {
    #pragma unroll
    for (int r = 0; r < 4; ++r) {
      float v = accS[m][r] * accS[m][r] - q[m][r];
      v += __shfl_xor(v, 1, 64);
      v += __shfl_xor(v, 2, 64);
      v += __shfl_xor(v, 4, 64);
      v += __shfl_xor(v, 8, 64);
      if (c16 == 0) s_fm[wave][m * 16 + quad * 4 + r] = v;
    }
  }
  // ---- epilogue 3: first-order term, 8 threads per row
  {
    int row = tid >> 3, fi = tid & 7;
    float lv = 0.f;
    for (int f = fi; f < NF; f += 8)
      lv += lin_table[(int)s_x[row * NF + f] + f * FD];
    lv += __shfl_xor(lv, 1, 64);
    lv += __shfl_xor(lv, 2, 64);
    lv += __shfl_xor(lv, 4, 64);
    if (fi == 0) s_lin[row] = lv;
  }
  __syncthreads();
  if (tid < 32)
    base[b0 + tid] = s_lin[tid] + lin_bias[0]
                   + 0.5f * (s_fm[0][tid] + s_fm[1][tid]
                           + s_fm[2][tid] + s_fm[3][tid]);
}

// ---------------------------------------------------------------------------
// MLP GEMM (layers 2,3), m97-style: global_load_lds(16B) staging, XOR-swizzled
// unpadded LDS, tile 128x80xBK64. C = relu((A@B + b)*BN_INV*g + be). K=kit*64.
// ---------------------------------------------------------------------------
__global__ __launch_bounds__(256) void k_gemm(
    const u16* __restrict__ A, int lda, const u16* __restrict__ Bt, int ldb,
    int kit, const float* __restrict__ bias, const float* __restrict__ g,
    const float* __restrict__ be, u16* __restrict__ C, int ldc)
{
  __shared__ __align__(16) u16 sA[128 * 64];
  __shared__ __align__(16) u16 sB[80 * 64];

  const int tid = threadIdx.x;
  int bid = blockIdx.x;
  int xcd = bid & 7;
  int j = bid >> 3;
  const int m0 = (xcd * 16 + j / 5) * 128;
  const int n0 = (j % 5) * 80;

  const int wave = tid >> 6, lane = tid & 63;
  const int quad = lane >> 4, c16 = lane & 15;

  const int srow = lane >> 3;
  const int sclog = (lane & 7) ^ (srow & 7);
  const u16* gA = A + (long)m0 * lda + sclog * 8;
  const u16* gB = Bt + (long)n0 * ldb + sclog * 8;

  f32x4 acc[2][5];
  #pragma unroll
  for (int mtt = 0; mtt < 2; ++mtt)
    #pragma unroll
    for (int nt = 0; nt < 5; ++nt) acc[mtt][nt] = {0.f, 0.f, 0.f, 0.f};

  for (int kk = 0; kk < kit; ++kk) {
    const int k0 = kk * 64;
    #pragma unroll
    for (int it = 0; it < 4; ++it) {
      int s = wave * 4 + it;
      gld16(gA + (long)(s * 8 + srow) * lda + k0, &sA[s * 512]);
    }
    gld16(gB + (long)(wave * 8 + srow) * ldb + k0, &sB[wave * 512]);
    gld16(gB + (long)((wave + 4) * 8 + srow) * ldb + k0, &sB[(wave + 4) * 512]);
    if (wave < 2)
      gld16(gB + (long)((wave + 8) * 8 + srow) * ldb + k0, &sB[(wave + 8) * 512]);
    __syncthreads();

    #pragma unroll
    for (int ks = 0; ks < 2; ++ks) {
      const int co = ((ks * 4 + quad) ^ (c16 & 7)) * 8;
      bf16x8 a0 = *(const bf16x8*)&sA[(wave * 32 + c16) * 64 + co];
      bf16x8 a1 = *(const bf16x8*)&sA[(wave * 32 + 16 + c16) * 64 + co];
      #pragma unroll
      for (int nt = 0; nt < 5; ++nt) {
        bf16x8 b = *(const bf16x8*)&sB[(nt * 16 + c16) * 64 + co];
        acc[0][nt] = __builtin_amdgcn_mfma_f32_16x16x32_bf16(a0, b, acc[0][nt], 0, 0, 0);
        acc[1][nt] = __builtin_amdgcn_mfma_f32_16x16x32_bf16(a1, b, acc[1][nt], 0, 0, 0);
      }
    }
    __syncthreads();
  }

  const float BN_INV = 0.9999950000374997f;
  #pragma unroll
  for (int nt = 0; nt < 5; ++nt) {
    int col = n0 + nt * 16 + c16;
    float bb = bias[col];
    float sc = BN_INV * g[col];
    float bv = be[col];
    #pragma unroll
    for (int mtt = 0; mtt < 2; ++mtt) {
      #pragma unroll
      for (int r = 0; r < 4; ++r) {
        int row = m0 + wave * 32 + mtt * 16 + quad * 4 + r;
        float y = (acc[mtt][nt][r] + bb) * sc + bv;
        y = fmaxf(y, 0.f);
        C[(long)row * ldc + col] = f2bf(y);
      }
    }
  }
  if (ldc > 400 && n0 == 320) {
    int npad = ldc - 400;
    for (int s = tid; s < 128 * npad; s += 256) {
      int rr = s / npad, cc = s % npad;
      C[(long)(m0 + rr) * ldc + 400 + cc] = 0;
    }
  }
}

// ---------------------------------------------------------------------------
// Final: out[b] = sigmoid(base[b] + h3[b,:].Wout + bout). One wave per row.
// ---------------------------------------------------------------------------
__global__ __launch_bounds__(256) void k_final(
    const u16* __restrict__ h3, const float* __restrict__ Wout,
    const float* __restrict__ bout, const float* __restrict__ base,
    float* __restrict__ out)
{
  int wave = threadIdx.x >> 6, lane = threadIdx.x & 63;
  int b = blockIdx.x * 4 + wave;
  float s = 0.f;
  for (int jj = lane; jj < 400; jj += 64)
    s += bf2f(h3[(long)b * 448 + jj]) * Wout[jj];
  #pragma unroll
  for (int m = 32; m >= 1; m >>= 1) s += __shfl_xor(s, m, 64);
  if (lane == 0) {
    float z = s + base[b] + bout[0];
    out[b] = 1.0f / (1.0f + __expf(-z));
  }
}

extern "C" void kernel_launch(void* const* d_in, const int* in_sizes, int n_in,
                              void* d_out, int out_size, void* d_ws, size_t ws_size,
                              hipStream_t stream)
{
  const int*   x         = (const int*)d_in[0];
  const float* emb       = (const float*)d_in[1];
  const float* lin_table = (const float*)d_in[2];
  const float* lin_bias  = (const float*)d_in[3];
  const float* svar      = (const float*)d_in[4];
  const float* Wt        = (const float*)d_in[5];
  const float* bt        = (const float*)d_in[6];
  const float* W1  = (const float*)d_in[7];
  const float* b1  = (const float*)d_in[8];
  const float* g1  = (const float*)d_in[9];
  const float* be1 = (const float*)d_in[10];
  const float* W2  = (const float*)d_in[11];
  const float* b2  = (const float*)d_in[12];
  const float* g2  = (const float*)d_in[13];
  const float* be2 = (const float*)d_in[14];
  const float* W3  = (const float*)d_in[15];
  const float* b3  = (const float*)d_in[16];
  const float* g3  = (const float*)d_in[17];
  const float* be3 = (const float*)d_in[18];
  const float* Wo  = (const float*)d_in[19];
  const float* bo  = (const float*)d_in[20];

  char* ws = (char*)d_ws;
  size_t off = 0;
  u16* h1 = (u16*)(ws + off);     off += (size_t)BT * 448 * 2;
  u16* h2 = (u16*)(ws + off);     off += (size_t)BT * 448 * 2;
  u16* h3 = (u16*)(ws + off);     off += (size_t)BT * 448 * 2;
  float* base = (float*)(ws + off); off += (size_t)BT * 4;
  u16* W1T = (u16*)(ws + off);    off += (size_t)448 * 2496 * 2;
  u16* W2T = (u16*)(ws + off);    off += (size_t)448 * 448 * 2;
  u16* W3T = (u16*)(ws + off);    off += (size_t)448 * 448 * 2;
  u16* Wtb = (u16*)(ws + off);    off += (size_t)NF * 4096 * 2;
  (void)ws_size; (void)in_sizes; (void)n_in; (void)out_size;

  k_prep<<<dim3(14, 78, 4), 256, 0, stream>>>(W1, W1T, W2, W2T, W3, W3T, Wt, Wtb);
  k_embed_mlp1<<<512, 256, 0, stream>>>(x, emb, lin_table, lin_bias, svar, Wtb,
                                        bt, W1T, b1, g1, be1, h1, base);
  k_gemm<<<640, 256, 0, stream>>>(h1, 448, W2T, 448, 7, b2, g2, be2, h2, 448);
  k_gemm<<<640, 256, 0, stream>>>(h2, 448, W3T, 448, 7, b3, g3, be3, h3, 448);
  k_final<<<4096, 256, 0, stream>>>(h3, Wo, bo, base, (float*)d_out);
}

// Round 5
// 503.854 us; speedup vs baseline: 2.0439x; 1.0596x over previous
//
#include <hip/hip_runtime.h>

#define BT 16384
#define NF 39
#define FD 26000

typedef unsigned short u16;
typedef unsigned int u32;
typedef short bf16x8 __attribute__((ext_vector_type(8)));
typedef float f32x4 __attribute__((ext_vector_type(4)));

__device__ __forceinline__ float bf2f(u16 h) {
  union { u32 u; float f; } v; v.u = ((u32)h) << 16; return v.f;
}
__device__ __forceinline__ u16 f2bf(float f) {
  union { float f; u32 u; } v; v.f = f;
  u32 r = v.u + 0x7fffu + ((v.u >> 16) & 1u);
  return (u16)(r >> 16);
}
// async global->LDS, 16B/lane; LDS dest = wave-uniform base + lane*16.
__device__ __forceinline__ void gld16(const u16* g, u16* l) {
  __builtin_amdgcn_global_load_lds(
      (const __attribute__((address_space(1))) void*)g,
      (__attribute__((address_space(3))) void*)l, 16, 0, 0);
}

// ---------------------------------------------------------------------------
// prep: z=0..2 transpose+cast W1/W2/W3 (f32 [K][400] -> bf16 [400+][Kpad],
// K-pad zero, rows 400..447 zero);  z=3 cast Wt -> bf16 (row-major).
// ---------------------------------------------------------------------------
__global__ __launch_bounds__(256) void k_prep(
    const float* __restrict__ W1, u16* __restrict__ W1T,
    const float* __restrict__ W2, u16* __restrict__ W2T,
    const float* __restrict__ W3, u16* __restrict__ W3T,
    const float* __restrict__ Wt, u16* __restrict__ Wtb)
{
  int z = blockIdx.z;
  if (z == 3) {
    int idx = (blockIdx.y * 14 + blockIdx.x) * 256 + threadIdx.x;
    if (idx < NF * 4096) Wtb[idx] = f2bf(Wt[idx]);
    return;
  }
  const float* in = (z == 0) ? W1 : (z == 1) ? W2 : W3;
  u16* outp = (z == 0) ? W1T : (z == 1) ? W2T : W3T;
  int K = (z == 0) ? 2496 : 400;
  int Kpad = (z == 0) ? 2496 : 448;
  int r0 = blockIdx.y * 32, c0 = blockIdx.x * 32;
  if (r0 >= Kpad) return;
  __shared__ u16 t[32][33];
  int tx = threadIdx.x & 31, ty = threadIdx.x >> 5;
  for (int i = ty; i < 32; i += 8) {
    int r = r0 + i, c = c0 + tx;
    t[i][tx] = (r < K && c < 400) ? f2bf(in[(long)r * 400 + c]) : (u16)0;
  }
  __syncthreads();
  int r = r0 + tx;
  if (r < Kpad)
    for (int i = ty; i < 32; i += 8)
      outp[(long)(c0 + i) * Kpad + r] = t[tx][i];
}

// ---------------------------------------------------------------------------
// k_embed v3: barrier-free field loop.  1024 blocks x 16 rows; 4 waves split
// the 39 fields 4-ways (f = wave, wave+4, ...).  Each lane gathers its own
// A-fragment directly from emb (lane(c16,quad) -> row c16, cols quad*8/+32:
// 64B, a wave covers 16 rows x 256B with no duplication), gates+packs in
// registers, stores h0 (full-line coalesced per store instr), and runs the
// 4 FM trans MFMAs for all 64 Wt output cols.  No LDS staging, no barriers
// in the loop -> gather latency hidden by 16 waves/CU + 1-field prefetch.
// FM col-sums are merged across the 4 field-phases via LDS at the end
// (sum BEFORE squaring), then (S^2 - q) is lane-reduced as in round-0.
// LDS 35.8KB, launch_bounds(256,4) -> 4 blocks/CU, VGPR<=128.
// ---------------------------------------------------------------------------
__global__ __launch_bounds__(256, 4) void k_embed(
    const int* __restrict__ x, const float* __restrict__ emb,
    const float* __restrict__ lin_table, const float* __restrict__ lin_bias,
    const float* __restrict__ sparse_var, const u16* __restrict__ Wtb,
    const float* __restrict__ bt, u16* __restrict__ h0, float* __restrict__ base)
{
  __shared__ u16   s_x[16 * NF];       //  1248 B
  __shared__ float s_sv[NF * 64];      //  9984 B
  __shared__ float s_bt[NF * 64];      //  9984 B
  __shared__ float s_acc[3][16][64];   // 12288 B (field-phase partial col-sums)
  __shared__ float s_q[3][4][64];      //  3072 B
  __shared__ float s_fm[16];           //    64 B
  __shared__ float s_lin[16];          //    64 B   -> 35.8 KB

  const int tid = threadIdx.x;
  const int b0 = blockIdx.x * 16;

  for (int i = tid; i < 16 * NF; i += 256) s_x[i] = (u16)x[b0 * NF + i];
  for (int i = tid; i < NF * 64; i += 256) {
    float v = sparse_var[i];
    float s = 1.0f / (1.0f + __expf(-15.0f * v));
    s_sv[i] = (s > 0.001f) ? s : 0.0f;
    s_bt[i] = bt[i];
  }
  __syncthreads();

  const int wave = tid >> 6, lane = tid & 63;
  const int quad = lane >> 4, c16 = lane & 15;

  float accS[4][4], q[4];               // [colgroup][r] FM col-sums; sq-sums
  #pragma unroll
  for (int cg = 0; cg < 4; ++cg)
    #pragma unroll
    for (int r = 0; r < 4; ++r) accS[cg][r] = 0.f;
  #pragma unroll
  for (int r = 0; r < 4; ++r) q[r] = 0.f;

  const u16* xrow = &s_x[c16 * NF];
  u16* hrow = h0 + (long)(b0 + c16) * 2496 + quad * 8;

  // prologue: gather this wave's first field (wave < 4 <= NF always)
  float4 c0, c1, c2, c3;
  {
    long gi = (long)((int)xrow[wave] + wave * FD);
    const float* src = emb + gi * 64 + quad * 8;
    c0 = *(const float4*)(src);
    c1 = *(const float4*)(src + 4);
    c2 = *(const float4*)(src + 32);
    c3 = *(const float4*)(src + 36);
  }

  for (int f = wave; f < NF; f += 4) {
    // prefetch next field of this phase
    float4 n0, n1, n2, n3;
    if (f + 4 < NF) {
      long gi = (long)((int)xrow[f + 4] + (f + 4) * FD);
      const float* src = emb + gi * 64 + quad * 8;
      n0 = *(const float4*)(src);
      n1 = *(const float4*)(src + 4);
      n2 = *(const float4*)(src + 32);
      n3 = *(const float4*)(src + 36);
    }

    // gate + pack A-frags (row c16, k-chunks quad*8 and 32+quad*8)
    const float* sv = &s_sv[f * 64 + quad * 8];
    union { uint4 v; u16 h[8]; } pa, pb;
    pa.h[0] = f2bf(c0.x * sv[0]);  pa.h[1] = f2bf(c0.y * sv[1]);
    pa.h[2] = f2bf(c0.z * sv[2]);  pa.h[3] = f2bf(c0.w * sv[3]);
    pa.h[4] = f2bf(c1.x * sv[4]);  pa.h[5] = f2bf(c1.y * sv[5]);
    pa.h[6] = f2bf(c1.z * sv[6]);  pa.h[7] = f2bf(c1.w * sv[7]);
    pb.h[0] = f2bf(c2.x * sv[32]); pb.h[1] = f2bf(c2.y * sv[33]);
    pb.h[2] = f2bf(c2.z * sv[34]); pb.h[3] = f2bf(c2.w * sv[35]);
    pb.h[4] = f2bf(c3.x * sv[36]); pb.h[5] = f2bf(c3.y * sv[37]);
    pb.h[6] = f2bf(c3.z * sv[38]); pb.h[7] = f2bf(c3.w * sv[39]);
    *(uint4*)(hrow + f * 64) = pa.v;        // full 64B line per store instr
    *(uint4*)(hrow + f * 64 + 32) = pb.v;
    bf16x8 a0 = *(bf16x8*)&pa;
    bf16x8 a1 = *(bf16x8*)&pb;

    // FM trans MFMA over all 4 col-groups (B from L2-resident Wtb)
    const u16* wf = Wtb + f * 4096 + c16 * 64 + quad * 8;
    const float* btf = &s_bt[f * 64 + c16];
    #pragma unroll
    for (int cg = 0; cg < 4; ++cg) {
      bf16x8 bb0 = *(const bf16x8*)(wf + cg * 1024);
      bf16x8 bb1 = *(const bf16x8*)(wf + cg * 1024 + 32);
      f32x4 t = {0.f, 0.f, 0.f, 0.f};
      t = __builtin_amdgcn_mfma_f32_16x16x32_bf16(a0, bb0, t, 0, 0, 0);
      t = __builtin_amdgcn_mfma_f32_16x16x32_bf16(a1, bb1, t, 0, 0, 0);
      float btv = btf[cg * 16];
      #pragma unroll
      for (int r = 0; r < 4; ++r) {
        float tv = t[r] + btv;
        accS[cg][r] += tv;
        q[r] += tv * tv;
      }
    }
    c0 = n0; c1 = n1; c2 = n2; c3 = n3;
  }

  // ---- merge the 4 field-phase partials (sum BEFORE squaring)
  if (wave != 0) {
    #pragma unroll
    for (int cg = 0; cg < 4; ++cg)
      #pragma unroll
      for (int r = 0; r < 4; ++r)
        s_acc[wave - 1][cg * 4 + r][lane] = accS[cg][r];
    #pragma unroll
    for (int r = 0; r < 4; ++r) s_q[wave - 1][r][lane] = q[r];
  }
  // first-order term: 16 threads per row (independent of FM merge)
  {
    int lrow = tid >> 4, fi = tid & 15;
    float lv = 0.f;
    for (int f = fi; f < NF; f += 16)
      lv += lin_table[(int)s_x[lrow * NF + f] + f * FD];
    lv += __shfl_xor(lv, 1, 64);
    lv += __shfl_xor(lv, 2, 64);
    lv += __shfl_xor(lv, 4, 64);
    lv += __shfl_xor(lv, 8, 64);
    if (fi == 0) s_lin[lrow] = lv;
  }
  __syncthreads();
  if (wave == 0) {
    #pragma unroll
    for (int r = 0; r < 4; ++r) {
      float qT = q[r] + s_q[0][r][lane] + s_q[1][r][lane] + s_q[2][r][lane];
      float v = 0.f;
      #pragma unroll
      for (int cg = 0; cg < 4; ++cg) {
        float aT = accS[cg][r] + s_acc[0][cg * 4 + r][lane]
                 + s_acc[1][cg * 4 + r][lane] + s_acc[2][cg * 4 + r][lane];
        v += aT * aT;
      }
      v -= qT;
      v += __shfl_xor(v, 1, 64);
      v += __shfl_xor(v, 2, 64);
      v += __shfl_xor(v, 4, 64);
      v += __shfl_xor(v, 8, 64);
      if (c16 == 0) s_fm[quad * 4 + r] = v;   // row = quad*4+r (D mapping)
    }
  }
  __syncthreads();
  if (tid < 16)
    base[b0 + tid] = s_lin[tid] + lin_bias[0] + 0.5f * s_fm[tid];
}

// ---------------------------------------------------------------------------
// MLP GEMM, m97-style: global_load_lds(16B) staging, XOR-swizzled unpadded
// LDS, tile 128x80xBK64. C = relu((A@B + b)*BN_INV*g + be). K = kit*64.
// ---------------------------------------------------------------------------
__global__ __launch_bounds__(256) void k_gemm(
    const u16* __restrict__ A, int lda, const u16* __restrict__ Bt, int ldb,
    int kit, const float* __restrict__ bias, const float* __restrict__ g,
    const float* __restrict__ be, u16* __restrict__ C, int ldc)
{
  __shared__ __align__(16) u16 sA[128 * 64];
  __shared__ __align__(16) u16 sB[80 * 64];

  const int tid = threadIdx.x;
  int bid = blockIdx.x;
  int xcd = bid & 7;
  int j = bid >> 3;
  const int m0 = (xcd * 16 + j / 5) * 128;
  const int n0 = (j % 5) * 80;

  const int wave = tid >> 6, lane = tid & 63;
  const int quad = lane >> 4, c16 = lane & 15;

  const int srow = lane >> 3;
  const int sclog = (lane & 7) ^ (srow & 7);
  const u16* gA = A + (long)m0 * lda + sclog * 8;
  const u16* gB = Bt + (long)n0 * ldb + sclog * 8;

  f32x4 acc[2][5];
  #pragma unroll
  for (int mtt = 0; mtt < 2; ++mtt)
    #pragma unroll
    for (int nt = 0; nt < 5; ++nt) acc[mtt][nt] = {0.f, 0.f, 0.f, 0.f};

  for (int kk = 0; kk < kit; ++kk) {
    const int k0 = kk * 64;
    #pragma unroll
    for (int it = 0; it < 4; ++it) {
      int s = wave * 4 + it;
      gld16(gA + (long)(s * 8 + srow) * lda + k0, &sA[s * 512]);
    }
    gld16(gB + (long)(wave * 8 + srow) * ldb + k0, &sB[wave * 512]);
    gld16(gB + (long)((wave + 4) * 8 + srow) * ldb + k0, &sB[(wave + 4) * 512]);
    if (wave < 2)
      gld16(gB + (long)((wave + 8) * 8 + srow) * ldb + k0, &sB[(wave + 8) * 512]);
    __syncthreads();

    #pragma unroll
    for (int ks = 0; ks < 2; ++ks) {
      const int co = ((ks * 4 + quad) ^ (c16 & 7)) * 8;
      bf16x8 a0 = *(const bf16x8*)&sA[(wave * 32 + c16) * 64 + co];
      bf16x8 a1 = *(const bf16x8*)&sA[(wave * 32 + 16 + c16) * 64 + co];
      #pragma unroll
      for (int nt = 0; nt < 5; ++nt) {
        bf16x8 b = *(const bf16x8*)&sB[(nt * 16 + c16) * 64 + co];
        acc[0][nt] = __builtin_amdgcn_mfma_f32_16x16x32_bf16(a0, b, acc[0][nt], 0, 0, 0);
        acc[1][nt] = __builtin_amdgcn_mfma_f32_16x16x32_bf16(a1, b, acc[1][nt], 0, 0, 0);
      }
    }
    __syncthreads();
  }

  const float BN_INV = 0.9999950000374997f;
  #pragma unroll
  for (int nt = 0; nt < 5; ++nt) {
    int col = n0 + nt * 16 + c16;
    float bb = bias[col];
    float sc = BN_INV * g[col];
    float bv = be[col];
    #pragma unroll
    for (int mtt = 0; mtt < 2; ++mtt) {
      #pragma unroll
      for (int r = 0; r < 4; ++r) {
        int row = m0 + wave * 32 + mtt * 16 + quad * 4 + r;
        float y = (acc[mtt][nt][r] + bb) * sc + bv;
        y = fmaxf(y, 0.f);
        C[(long)row * ldc + col] = f2bf(y);
      }
    }
  }
  if (ldc > 400 && n0 == 320) {
    int npad = ldc - 400;
    for (int s = tid; s < 128 * npad; s += 256) {
      int rr = s / npad, cc = s % npad;
      C[(long)(m0 + rr) * ldc + 400 + cc] = 0;
    }
  }
}

// ---------------------------------------------------------------------------
// Final: out[b] = sigmoid(base[b] + h3[b,:].Wout + bout). One wave per row.
// ---------------------------------------------------------------------------
__global__ __launch_bounds__(256) void k_final(
    const u16* __restrict__ h3, const float* __restrict__ Wout,
    const float* __restrict__ bout, const float* __restrict__ base,
    float* __restrict__ out)
{
  int wave = threadIdx.x >> 6, lane = threadIdx.x & 63;
  int b = blockIdx.x * 4 + wave;
  float s = 0.f;
  for (int jj = lane; jj < 400; jj += 64)
    s += bf2f(h3[(long)b * 448 + jj]) * Wout[jj];
  #pragma unroll
  for (int m = 32; m >= 1; m >>= 1) s += __shfl_xor(s, m, 64);
  if (lane == 0) {
    float z = s + base[b] + bout[0];
    out[b] = 1.0f / (1.0f + __expf(-z));
  }
}

extern "C" void kernel_launch(void* const* d_in, const int* in_sizes, int n_in,
                              void* d_out, int out_size, void* d_ws, size_t ws_size,
                              hipStream_t stream)
{
  const int*   x         = (const int*)d_in[0];
  const float* emb       = (const float*)d_in[1];
  const float* lin_table = (const float*)d_in[2];
  const float* lin_bias  = (const float*)d_in[3];
  const float* svar      = (const float*)d_in[4];
  const float* Wt        = (const float*)d_in[5];
  const float* bt        = (const float*)d_in[6];
  const float* W1  = (const float*)d_in[7];
  const float* b1  = (const float*)d_in[8];
  const float* g1  = (const float*)d_in[9];
  const float* be1 = (const float*)d_in[10];
  const float* W2  = (const float*)d_in[11];
  const float* b2  = (const float*)d_in[12];
  const float* g2  = (const float*)d_in[13];
  const float* be2 = (const float*)d_in[14];
  const float* W3  = (const float*)d_in[15];
  const float* b3  = (const float*)d_in[16];
  const float* g3  = (const float*)d_in[17];
  const float* be3 = (const float*)d_in[18];
  const float* Wo  = (const float*)d_in[19];
  const float* bo  = (const float*)d_in[20];

  char* ws = (char*)d_ws;
  size_t off = 0;
  u16* h0 = (u16*)(ws + off);     off += (size_t)BT * 2496 * 2;   // 81.8 MB
  u16* h1 = (u16*)(ws + off);     off += (size_t)BT * 448 * 2;
  u16* h2 = (u16*)(ws + off);     off += (size_t)BT * 448 * 2;
  u16* h3 = (u16*)(ws + off);     off += (size_t)BT * 448 * 2;
  float* base = (float*)(ws + off); off += (size_t)BT * 4;
  u16* W1T = (u16*)(ws + off);    off += (size_t)448 * 2496 * 2;
  u16* W2T = (u16*)(ws + off);    off += (size_t)448 * 448 * 2;
  u16* W3T = (u16*)(ws + off);    off += (size_t)448 * 448 * 2;
  u16* Wtb = (u16*)(ws + off);    off += (size_t)NF * 4096 * 2;
  (void)ws_size; (void)in_sizes; (void)n_in; (void)out_size;

  k_prep<<<dim3(14, 78, 4), 256, 0, stream>>>(W1, W1T, W2, W2T, W3, W3T, Wt, Wtb);
  k_embed<<<1024, 256, 0, stream>>>(x, emb, lin_table, lin_bias, svar, Wtb, bt,
                                    h0, base);
  k_gemm<<<640, 256, 0, stream>>>(h0, 2496, W1T, 2496, 39, b1, g1, be1, h1, 448);
  k_gemm<<<640, 256, 0, stream>>>(h1, 448, W2T, 448, 7, b2, g2, be2, h2, 448);
  k_gemm<<<640, 256, 0, stream>>>(h2, 448, W3T, 448, 7, b3, g3, be3, h3, 448);
  k_final<<<4096, 256, 0, stream>>>(h3, Wo, bo, base, (float*)d_out);
}

// Round 6
// 492.388 us; speedup vs baseline: 2.0915x; 1.0233x over previous
//
#include <hip/hip_runtime.h>

#define BT 16384
#define NF 39
#define FD 26000

typedef unsigned short u16;
typedef unsigned int u32;
typedef short bf16x8 __attribute__((ext_vector_type(8)));
typedef float f32x4 __attribute__((ext_vector_type(4)));

__device__ __forceinline__ float bf2f(u16 h) {
  union { u32 u; float f; } v; v.u = ((u32)h) << 16; return v.f;
}
__device__ __forceinline__ u16 f2bf(float f) {
  union { float f; u32 u; } v; v.f = f;
  u32 r = v.u + 0x7fffu + ((v.u >> 16) & 1u);
  return (u16)(r >> 16);
}
// async global->LDS, 16B/lane; LDS dest = wave-uniform base + lane*16.
__device__ __forceinline__ void gld16(const u16* g, u16* l) {
  __builtin_amdgcn_global_load_lds(
      (const __attribute__((address_space(1))) void*)g,
      (__attribute__((address_space(3))) void*)l, 16, 0, 0);
}

// ---------------------------------------------------------------------------
// prep: z=0..2 transpose+cast W1/W2/W3 (f32 [K][400] -> bf16 [400+][Kpad],
// K-pad zero, rows 400..447 zero);  z=3 cast Wt -> bf16 in MFMA-FRAGMENT
// order: Wtb[f*4096 + cg*1024 + half*512 + lane*8 + j] =
//        Wt[f][cg*16 + (lane&15)][half*32 + (lane>>4)*8 + j]
// so k_embed's B-frag loads are 64-lane x 16B fully coalesced.
// ---------------------------------------------------------------------------
__global__ __launch_bounds__(256) void k_prep(
    const float* __restrict__ W1, u16* __restrict__ W1T,
    const float* __restrict__ W2, u16* __restrict__ W2T,
    const float* __restrict__ W3, u16* __restrict__ W3T,
    const float* __restrict__ Wt, u16* __restrict__ Wtb)
{
  int z = blockIdx.z;
  if (z == 3) {
    int idx = (blockIdx.y * 14 + blockIdx.x) * 256 + threadIdx.x;
    if (idx < NF * 4096) {
      int f = idx >> 12, r = idx & 4095;
      int cg = r >> 10, half = (r >> 9) & 1, l = (r >> 3) & 63, j = r & 7;
      int q = l >> 4, c = l & 15;
      Wtb[idx] = f2bf(Wt[f * 4096 + (cg * 16 + c) * 64 + half * 32 + q * 8 + j]);
    }
    return;
  }
  const float* in = (z == 0) ? W1 : (z == 1) ? W2 : W3;
  u16* outp = (z == 0) ? W1T : (z == 1) ? W2T : W3T;
  int K = (z == 0) ? 2496 : 400;
  int Kpad = (z == 0) ? 2496 : 448;
  int r0 = blockIdx.y * 32, c0 = blockIdx.x * 32;
  if (r0 >= Kpad) return;
  __shared__ u16 t[32][33];
  int tx = threadIdx.x & 31, ty = threadIdx.x >> 5;
  for (int i = ty; i < 32; i += 8) {
    int r = r0 + i, c = c0 + tx;
    t[i][tx] = (r < K && c < 400) ? f2bf(in[(long)r * 400 + c]) : (u16)0;
  }
  __syncthreads();
  int r = r0 + tx;
  if (r < Kpad)
    for (int i = ty; i < 32; i += 8)
      outp[(long)(c0 + i) * Kpad + r] = t[tx][i];
}

// ---------------------------------------------------------------------------
// k_embed v4: barrier-free field loop (as v3) + FRAGMENT-ORDERED Wtb so all
// B-frag loads are fully coalesced (v3's regression: c16*64-strided loads
// were 16-transaction scatters; this was ~25us).  1024 blocks x 16 rows;
// 4 waves split the 39 fields; lanes gather their own A-frags from emb,
// gate+pack in regs, store h0, run 4 FM trans MFMAs per field.  FM col-sums
// merged across field-phases via LDS at the end (sum BEFORE squaring).
// LDS 35.8KB, launch_bounds(256,4) -> 4 blocks/CU, 16 waves/CU.
// ---------------------------------------------------------------------------
__global__ __launch_bounds__(256, 4) void k_embed(
    const int* __restrict__ x, const float* __restrict__ emb,
    const float* __restrict__ lin_table, const float* __restrict__ lin_bias,
    const float* __restrict__ sparse_var, const u16* __restrict__ Wtb,
    const float* __restrict__ bt, u16* __restrict__ h0, float* __restrict__ base)
{
  __shared__ u16   s_x[16 * NF];       //  1248 B
  __shared__ float s_sv[NF * 64];      //  9984 B
  __shared__ float s_bt[NF * 64];      //  9984 B
  __shared__ float s_acc[3][16][64];   // 12288 B (field-phase partial col-sums)
  __shared__ float s_q[3][4][64];      //  3072 B
  __shared__ float s_fm[16];           //    64 B
  __shared__ float s_lin[16];          //    64 B   -> 35.8 KB

  const int tid = threadIdx.x;
  const int b0 = blockIdx.x * 16;

  for (int i = tid; i < 16 * NF; i += 256) s_x[i] = (u16)x[b0 * NF + i];
  for (int i = tid; i < NF * 64; i += 256) {
    float v = sparse_var[i];
    float s = 1.0f / (1.0f + __expf(-15.0f * v));
    s_sv[i] = (s > 0.001f) ? s : 0.0f;
    s_bt[i] = bt[i];
  }
  __syncthreads();

  const int wave = tid >> 6, lane = tid & 63;
  const int quad = lane >> 4, c16 = lane & 15;

  float accS[4][4], q[4];               // [colgroup][r] FM col-sums; sq-sums
  #pragma unroll
  for (int cg = 0; cg < 4; ++cg)
    #pragma unroll
    for (int r = 0; r < 4; ++r) accS[cg][r] = 0.f;
  #pragma unroll
  for (int r = 0; r < 4; ++r) q[r] = 0.f;

  const u16* xrow = &s_x[c16 * NF];
  u16* hrow = h0 + (long)(b0 + c16) * 2496 + quad * 8;
  const u16* wlane = Wtb + lane * 8;    // fragment-order base for this lane

  // prologue: gather this wave's first field (wave < 4 <= NF always)
  float4 c0, c1, c2, c3;
  {
    long gi = (long)((int)xrow[wave] + wave * FD);
    const float* src = emb + gi * 64 + quad * 8;
    c0 = *(const float4*)(src);
    c1 = *(const float4*)(src + 4);
    c2 = *(const float4*)(src + 32);
    c3 = *(const float4*)(src + 36);
  }

  for (int f = wave; f < NF; f += 4) {
    // prefetch next field of this phase
    float4 n0, n1, n2, n3;
    if (f + 4 < NF) {
      long gi = (long)((int)xrow[f + 4] + (f + 4) * FD);
      const float* src = emb + gi * 64 + quad * 8;
      n0 = *(const float4*)(src);
      n1 = *(const float4*)(src + 4);
      n2 = *(const float4*)(src + 32);
      n3 = *(const float4*)(src + 36);
    }

    // gate + pack A-frags (row c16, k-chunks quad*8 and 32+quad*8)
    const float* sv = &s_sv[f * 64 + quad * 8];
    union { uint4 v; u16 h[8]; } pa, pb;
    pa.h[0] = f2bf(c0.x * sv[0]);  pa.h[1] = f2bf(c0.y * sv[1]);
    pa.h[2] = f2bf(c0.z * sv[2]);  pa.h[3] = f2bf(c0.w * sv[3]);
    pa.h[4] = f2bf(c1.x * sv[4]);  pa.h[5] = f2bf(c1.y * sv[5]);
    pa.h[6] = f2bf(c1.z * sv[6]);  pa.h[7] = f2bf(c1.w * sv[7]);
    pb.h[0] = f2bf(c2.x * sv[32]); pb.h[1] = f2bf(c2.y * sv[33]);
    pb.h[2] = f2bf(c2.z * sv[34]); pb.h[3] = f2bf(c2.w * sv[35]);
    pb.h[4] = f2bf(c3.x * sv[36]); pb.h[5] = f2bf(c3.y * sv[37]);
    pb.h[6] = f2bf(c3.z * sv[38]); pb.h[7] = f2bf(c3.w * sv[39]);
    *(uint4*)(hrow + f * 64) = pa.v;
    *(uint4*)(hrow + f * 64 + 32) = pb.v;
    bf16x8 a0 = *(bf16x8*)&pa;
    bf16x8 a1 = *(bf16x8*)&pb;

    // FM trans MFMA over 4 col-groups; B-frags coalesced from frag-order Wtb
    const u16* wf = wlane + f * 4096;
    const float* btf = &s_bt[f * 64 + c16];
    #pragma unroll
    for (int cg = 0; cg < 4; ++cg) {
      bf16x8 bb0 = *(const bf16x8*)(wf + cg * 1024);
      bf16x8 bb1 = *(const bf16x8*)(wf + cg * 1024 + 512);
      f32x4 t = {0.f, 0.f, 0.f, 0.f};
      t = __builtin_amdgcn_mfma_f32_16x16x32_bf16(a0, bb0, t, 0, 0, 0);
      t = __builtin_amdgcn_mfma_f32_16x16x32_bf16(a1, bb1, t, 0, 0, 0);
      float btv = btf[cg * 16];
      #pragma unroll
      for (int r = 0; r < 4; ++r) {
        float tv = t[r] + btv;
        accS[cg][r] += tv;
        q[r] += tv * tv;
      }
    }
    c0 = n0; c1 = n1; c2 = n2; c3 = n3;
  }

  // ---- merge the 4 field-phase partials (sum BEFORE squaring)
  if (wave != 0) {
    #pragma unroll
    for (int cg = 0; cg < 4; ++cg)
      #pragma unroll
      for (int r = 0; r < 4; ++r)
        s_acc[wave - 1][cg * 4 + r][lane] = accS[cg][r];
    #pragma unroll
    for (int r = 0; r < 4; ++r) s_q[wave - 1][r][lane] = q[r];
  }
  // first-order term: 16 threads per row (independent of FM merge)
  {
    int lrow = tid >> 4, fi = tid & 15;
    float lv = 0.f;
    for (int f = fi; f < NF; f += 16)
      lv += lin_table[(int)s_x[lrow * NF + f] + f * FD];
    lv += __shfl_xor(lv, 1, 64);
    lv += __shfl_xor(lv, 2, 64);
    lv += __shfl_xor(lv, 4, 64);
    lv += __shfl_xor(lv, 8, 64);
    if (fi == 0) s_lin[lrow] = lv;
  }
  __syncthreads();
  if (wave == 0) {
    #pragma unroll
    for (int r = 0; r < 4; ++r) {
      float qT = q[r] + s_q[0][r][lane] + s_q[1][r][lane] + s_q[2][r][lane];
      float v = 0.f;
      #pragma unroll
      for (int cg = 0; cg < 4; ++cg) {
        float aT = accS[cg][r] + s_acc[0][cg * 4 + r][lane]
                 + s_acc[1][cg * 4 + r][lane] + s_acc[2][cg * 4 + r][lane];
        v += aT * aT;
      }
      v -= qT;
      v += __shfl_xor(v, 1, 64);
      v += __shfl_xor(v, 2, 64);
      v += __shfl_xor(v, 4, 64);
      v += __shfl_xor(v, 8, 64);
      if (c16 == 0) s_fm[quad * 4 + r] = v;   // row = quad*4+r (D mapping)
    }
  }
  __syncthreads();
  if (tid < 16)
    base[b0 + tid] = s_lin[tid] + lin_bias[0] + 0.5f * s_fm[tid];
}

// ---------------------------------------------------------------------------
// MLP GEMM, m97-style: global_load_lds(16B) staging, XOR-swizzled unpadded
// LDS, tile 128x80xBK64. C = relu((A@B + b)*BN_INV*g + be). K = kit*64.
// ---------------------------------------------------------------------------
__global__ __launch_bounds__(256) void k_gemm(
    const u16* __restrict__ A, int lda, const u16* __restrict__ Bt, int ldb,
    int kit, const float* __restrict__ bias, const float* __restrict__ g,
    const float* __restrict__ be, u16* __restrict__ C, int ldc)
{
  __shared__ __align__(16) u16 sA[128 * 64];
  __shared__ __align__(16) u16 sB[80 * 64];

  const int tid = threadIdx.x;
  int bid = blockIdx.x;
  int xcd = bid & 7;
  int j = bid >> 3;
  const int m0 = (xcd * 16 + j / 5) * 128;
  const int n0 = (j % 5) * 80;

  const int wave = tid >> 6, lane = tid & 63;
  const int quad = lane >> 4, c16 = lane & 15;

  const int srow = lane >> 3;
  const int sclog = (lane & 7) ^ (srow & 7);
  const u16* gA = A + (long)m0 * lda + sclog * 8;
  const u16* gB = Bt + (long)n0 * ldb + sclog * 8;

  f32x4 acc[2][5];
  #pragma unroll
  for (int mtt = 0; mtt < 2; ++mtt)
    #pragma unroll
    for (int nt = 0; nt < 5; ++nt) acc[mtt][nt] = {0.f, 0.f, 0.f, 0.f};

  for (int kk = 0; kk < kit; ++kk) {
    const int k0 = kk * 64;
    #pragma unroll
    for (int it = 0; it < 4; ++it) {
      int s = wave * 4 + it;
      gld16(gA + (long)(s * 8 + srow) * lda + k0, &sA[s * 512]);
    }
    gld16(gB + (long)(wave * 8 + srow) * ldb + k0, &sB[wave * 512]);
    gld16(gB + (long)((wave + 4) * 8 + srow) * ldb + k0, &sB[(wave + 4) * 512]);
    if (wave < 2)
      gld16(gB + (long)((wave + 8) * 8 + srow) * ldb + k0, &sB[(wave + 8) * 512]);
    __syncthreads();

    #pragma unroll
    for (int ks = 0; ks < 2; ++ks) {
      const int co = ((ks * 4 + quad) ^ (c16 & 7)) * 8;
      bf16x8 a0 = *(const bf16x8*)&sA[(wave * 32 + c16) * 64 + co];
      bf16x8 a1 = *(const bf16x8*)&sA[(wave * 32 + 16 + c16) * 64 + co];
      #pragma unroll
      for (int nt = 0; nt < 5; ++nt) {
        bf16x8 b = *(const bf16x8*)&sB[(nt * 16 + c16) * 64 + co];
        acc[0][nt] = __builtin_amdgcn_mfma_f32_16x16x32_bf16(a0, b, acc[0][nt], 0, 0, 0);
        acc[1][nt] = __builtin_amdgcn_mfma_f32_16x16x32_bf16(a1, b, acc[1][nt], 0, 0, 0);
      }
    }
    __syncthreads();
  }

  const float BN_INV = 0.9999950000374997f;
  #pragma unroll
  for (int nt = 0; nt < 5; ++nt) {
    int col = n0 + nt * 16 + c16;
    float bb = bias[col];
    float sc = BN_INV * g[col];
    float bv = be[col];
    #pragma unroll
    for (int mtt = 0; mtt < 2; ++mtt) {
      #pragma unroll
      for (int r = 0; r < 4; ++r) {
        int row = m0 + wave * 32 + mtt * 16 + quad * 4 + r;
        float y = (acc[mtt][nt][r] + bb) * sc + bv;
        y = fmaxf(y, 0.f);
        C[(long)row * ldc + col] = f2bf(y);
      }
    }
  }
  if (ldc > 400 && n0 == 320) {
    int npad = ldc - 400;
    for (int s = tid; s < 128 * npad; s += 256) {
      int rr = s / npad, cc = s % npad;
      C[(long)(m0 + rr) * ldc + 400 + cc] = 0;
    }
  }
}

// ---------------------------------------------------------------------------
// Final: out[b] = sigmoid(base[b] + h3[b,:].Wout + bout). One wave per row.
// ---------------------------------------------------------------------------
__global__ __launch_bounds__(256) void k_final(
    const u16* __restrict__ h3, const float* __restrict__ Wout,
    const float* __restrict__ bout, const float* __restrict__ base,
    float* __restrict__ out)
{
  int wave = threadIdx.x >> 6, lane = threadIdx.x & 63;
  int b = blockIdx.x * 4 + wave;
  float s = 0.f;
  for (int jj = lane; jj < 400; jj += 64)
    s += bf2f(h3[(long)b * 448 + jj]) * Wout[jj];
  #pragma unroll
  for (int m = 32; m >= 1; m >>= 1) s += __shfl_xor(s, m, 64);
  if (lane == 0) {
    float z = s + base[b] + bout[0];
    out[b] = 1.0f / (1.0f + __expf(-z));
  }
}

extern "C" void kernel_launch(void* const* d_in, const int* in_sizes, int n_in,
                              void* d_out, int out_size, void* d_ws, size_t ws_size,
                              hipStream_t stream)
{
  const int*   x         = (const int*)d_in[0];
  const float* emb       = (const float*)d_in[1];
  const float* lin_table = (const float*)d_in[2];
  const float* lin_bias  = (const float*)d_in[3];
  const float* svar      = (const float*)d_in[4];
  const float* Wt        = (const float*)d_in[5];
  const float* bt        = (const float*)d_in[6];
  const float* W1  = (const float*)d_in[7];
  const float* b1  = (const float*)d_in[8];
  const float* g1  = (const float*)d_in[9];
  const float* be1 = (const float*)d_in[10];
  const float* W2  = (const float*)d_in[11];
  const float* b2  = (const float*)d_in[12];
  const float* g2  = (const float*)d_in[13];
  const float* be2 = (const float*)d_in[14];
  const float* W3  = (const float*)d_in[15];
  const float* b3  = (const float*)d_in[16];
  const float* g3  = (const float*)d_in[17];
  const float* be3 = (const float*)d_in[18];
  const float* Wo  = (const float*)d_in[19];
  const float* bo  = (const float*)d_in[20];

  char* ws = (char*)d_ws;
  size_t off = 0;
  u16* h0 = (u16*)(ws + off);     off += (size_t)BT * 2496 * 2;   // 81.8 MB
  u16* h1 = (u16*)(ws + off);     off += (size_t)BT * 448 * 2;
  u16* h2 = (u16*)(ws + off);     off += (size_t)BT * 448 * 2;
  u16* h3 = (u16*)(ws + off);     off += (size_t)BT * 448 * 2;
  float* base = (float*)(ws + off); off += (size_t)BT * 4;
  u16* W1T = (u16*)(ws + off);    off += (size_t)448 * 2496 * 2;
  u16* W2T = (u16*)(ws + off);    off += (size_t)448 * 448 * 2;
  u16* W3T = (u16*)(ws + off);    off += (size_t)448 * 448 * 2;
  u16* Wtb = (u16*)(ws + off);    off += (size_t)NF * 4096 * 2;
  (void)ws_size; (void)in_sizes; (void)n_in; (void)out_size;

  k_prep<<<dim3(14, 78, 4), 256, 0, stream>>>(W1, W1T, W2, W2T, W3, W3T, Wt, Wtb);
  k_embed<<<1024, 256, 0, stream>>>(x, emb, lin_table, lin_bias, svar, Wtb, bt,
                                    h0, base);
  k_gemm<<<640, 256, 0, stream>>>(h0, 2496, W1T, 2496, 39, b1, g1, be1, h1, 448);
  k_gemm<<<640, 256, 0, stream>>>(h1, 448, W2T, 448, 7, b2, g2, be2, h2, 448);
  k_gemm<<<640, 256, 0, stream>>>(h2, 448, W3T, 448, 7, b3, g3, be3, h3, 448);
  k_final<<<4096, 256, 0, stream>>>(h3, Wo, bo, base, (float*)d_out);
}

// Round 9
// 473.070 us; speedup vs baseline: 2.1769x; 1.0408x over previous
//
#include <hip/hip_runtime.h>

#define BT 16384
#define NF 39
#define FD 26000

typedef unsigned short u16;
typedef unsigned int u32;
typedef short bf16x8 __attribute__((ext_vector_type(8)));
typedef float f32x4 __attribute__((ext_vector_type(4)));

__device__ __forceinline__ float bf2f(u16 h) {
  union { u32 u; float f; } v; v.u = ((u32)h) << 16; return v.f;
}
__device__ __forceinline__ u16 f2bf(float f) {
  union { float f; u32 u; } v; v.f = f;
  u32 r = v.u + 0x7fffu + ((v.u >> 16) & 1u);
  return (u16)(r >> 16);
}
// async global->LDS, 16B/lane; LDS dest = wave-uniform base + lane*16.
__device__ __forceinline__ void gld16(const u16* g, u16* l) {
  __builtin_amdgcn_global_load_lds(
      (const __attribute__((address_space(1))) void*)g,
      (__attribute__((address_space(3))) void*)l, 16, 0, 0);
}

// ---------------------------------------------------------------------------
// prep: z=0..2 transpose+cast W1/W2/W3 (f32 [K][400] -> bf16 [400+][Kpad],
// K-pad zero);  z=3 cast Wt -> bf16 (row-major, unchanged layout).
// ---------------------------------------------------------------------------
__global__ __launch_bounds__(256) void k_prep(
    const float* __restrict__ W1, u16* __restrict__ W1T,
    const float* __restrict__ W2, u16* __restrict__ W2T,
    const float* __restrict__ W3, u16* __restrict__ W3T,
    const float* __restrict__ Wt, u16* __restrict__ Wtb)
{
  int z = blockIdx.z;
  if (z == 3) {
    int idx = (blockIdx.y * 14 + blockIdx.x) * 256 + threadIdx.x;
    if (idx < NF * 4096) Wtb[idx] = f2bf(Wt[idx]);
    return;
  }
  const float* in = (z == 0) ? W1 : (z == 1) ? W2 : W3;
  u16* outp = (z == 0) ? W1T : (z == 1) ? W2T : W3T;
  int K = (z == 0) ? 2496 : 400;
  int Kpad = (z == 0) ? 2496 : 448;
  int r0 = blockIdx.y * 32, c0 = blockIdx.x * 32;
  if (r0 >= Kpad) return;
  __shared__ u16 t[32][33];
  int tx = threadIdx.x & 31, ty = threadIdx.x >> 5;
  for (int i = ty; i < 32; i += 8) {
    int r = r0 + i, c = c0 + tx;
    t[i][tx] = (r < K && c < 400) ? f2bf(in[(long)r * 400 + c]) : (u16)0;
  }
  __syncthreads();
  int r = r0 + tx;
  if (r < Kpad)
    for (int i = ty; i < 32; i += 8)
      outp[(long)(c0 + i) * Kpad + r] = t[tx][i];   // rows >=400 are scratch-pad
}

// ---------------------------------------------------------------------------
// k_embed (round-0 proven version): gather+gate -> h0 (bf16) + per-field
// 64x64 linear (MFMA) for FM + first-order term. 512 blocks x 32 rows;
// double-buffered LDS, 1 barrier/field; Wt staged async with XOR chunk
// swizzle (conflict-free B-frag reads).
// ---------------------------------------------------------------------------
__global__ __launch_bounds__(256) void k_embed(
    const int* __restrict__ x, const float* __restrict__ emb,
    const float* __restrict__ lin_table, const float* __restrict__ lin_bias,
    const float* __restrict__ sparse_var, const u16* __restrict__ Wtb,
    const float* __restrict__ bt, u16* __restrict__ h0, float* __restrict__ base)
{
  __shared__ u16                s_x[32 * NF];        // 2496 B
  __shared__ float              s_sv[NF * 64];       // 9984 B
  __shared__ float              s_bt[NF * 64];       // 9984 B
  __shared__ __align__(16) u16  s_emb[2][32 * 72];   // 9216 B (stride 72)
  __shared__ __align__(16) u16  s_wt[2][64 * 64];    // 16384 B (chunk-swizzled)
  __shared__ float              s_fm[64];            // 256 B
  __shared__ float              s_lin[32];           // 128 B  -> 48448 B, 3 blk/CU

  const int tid = threadIdx.x;
  const int b0 = blockIdx.x * 32;

  for (int i = tid; i < 32 * NF; i += 256) s_x[i] = (u16)x[b0 * NF + i];
  for (int i = tid; i < NF * 64; i += 256) {
    float v = sparse_var[i];
    float s = 1.0f / (1.0f + __expf(-15.0f * v));
    s_sv[i] = (s > 0.001f) ? s : 0.0f;
    s_bt[i] = bt[i];
  }
  __syncthreads();

  const int wave = tid >> 6, lane = tid & 63;
  const int quad = lane >> 4, c16 = lane & 15;
  const int mt = wave & 1, nh = wave >> 1;
  const int g_row = tid >> 3, g_c8 = (tid & 7) * 8;
  // Wt staging: lane -> (row_rel = lane>>3, phys chunk = lane&7); fetch
  // logical chunk (lane&7)^row_rel so phys p at row r holds logical p^(r&7).
  const int wrow = lane >> 3;
  const int wchk = (lane & 7) ^ wrow;

  float q[4] = {0.f, 0.f, 0.f, 0.f};
  float accS[2][4] = {{0.f,0.f,0.f,0.f},{0.f,0.f,0.f,0.f}};

  // ---- prologue: stage field 0
  #pragma unroll
  for (int i = 0; i < 2; ++i) {
    int ii = wave * 2 + i;
    gld16(Wtb + (ii * 8 + wrow) * 64 + wchk * 8, &s_wt[0][ii * 512]);
  }
  {
    long gi = (long)((int)s_x[g_row * NF + 0]);
    float4 e0 = *(const float4*)&emb[gi * 64 + g_c8];
    float4 e1 = *(const float4*)&emb[gi * 64 + g_c8 + 4];
    union { uint4 v; u16 h[8]; } p;
    p.h[0] = f2bf(e0.x * s_sv[g_c8 + 0]);
    p.h[1] = f2bf(e0.y * s_sv[g_c8 + 1]);
    p.h[2] = f2bf(e0.z * s_sv[g_c8 + 2]);
    p.h[3] = f2bf(e0.w * s_sv[g_c8 + 3]);
    p.h[4] = f2bf(e1.x * s_sv[g_c8 + 4]);
    p.h[5] = f2bf(e1.y * s_sv[g_c8 + 5]);
    p.h[6] = f2bf(e1.z * s_sv[g_c8 + 6]);
    p.h[7] = f2bf(e1.w * s_sv[g_c8 + 7]);
    *(uint4*)&s_emb[0][g_row * 72 + g_c8] = p.v;
    *(uint4*)&h0[(long)(b0 + g_row) * 2496 + g_c8] = p.v;
  }
  __syncthreads();

  for (int f = 0; f < NF; ++f) {
    const int cur = f & 1, nxt = cur ^ 1;
    float4 e0, e1;
    const bool more = (f + 1) < NF;
    if (more) {
      // async-stage next Wt; prefetch next gather into regs
      #pragma unroll
      for (int i = 0; i < 2; ++i) {
        int ii = wave * 2 + i;
        gld16(Wtb + (f + 1) * 4096 + (ii * 8 + wrow) * 64 + wchk * 8,
              &s_wt[nxt][ii * 512]);
      }
      long gi = (long)((int)s_x[g_row * NF + f + 1] + (f + 1) * FD);
      e0 = *(const float4*)&emb[gi * 64 + g_c8];
      e1 = *(const float4*)&emb[gi * 64 + g_c8 + 4];
    }

    // FM trans MFMA on buffers[cur]
    bf16x8 a0 = *(const bf16x8*)&s_emb[cur][(mt * 16 + c16) * 72 + quad * 8];
    bf16x8 a1 = *(const bf16x8*)&s_emb[cur][(mt * 16 + c16) * 72 + 32 + quad * 8];
    #pragma unroll
    for (int j = 0; j < 2; ++j) {
      int row = (nh * 2 + j) * 16 + c16;
      int pc0 = quad ^ (row & 7);
      int pc1 = (quad + 4) ^ (row & 7);
      bf16x8 bb0 = *(const bf16x8*)&s_wt[cur][row * 64 + pc0 * 8];
      bf16x8 bb1 = *(const bf16x8*)&s_wt[cur][row * 64 + pc1 * 8];
      f32x4 acc = {0.f, 0.f, 0.f, 0.f};
      acc = __builtin_amdgcn_mfma_f32_16x16x32_bf16(a0, bb0, acc, 0, 0, 0);
      acc = __builtin_amdgcn_mfma_f32_16x16x32_bf16(a1, bb1, acc, 0, 0, 0);
      float btv = s_bt[f * 64 + row];
      #pragma unroll
      for (int r = 0; r < 4; ++r) {
        float t = acc[r] + btv;
        accS[j][r] += t;
        q[r] += t * t;
      }
    }

    if (more) {
      union { uint4 v; u16 h[8]; } p;
      const float* sv = &s_sv[(f + 1) * 64 + g_c8];
      p.h[0] = f2bf(e0.x * sv[0]);
      p.h[1] = f2bf(e0.y * sv[1]);
      p.h[2] = f2bf(e0.z * sv[2]);
      p.h[3] = f2bf(e0.w * sv[3]);
      p.h[4] = f2bf(e1.x * sv[4]);
      p.h[5] = f2bf(e1.y * sv[5]);
      p.h[6] = f2bf(e1.z * sv[6]);
      p.h[7] = f2bf(e1.w * sv[7]);
      *(uint4*)&s_emb[nxt][g_row * 72 + g_c8] = p.v;
      *(uint4*)&h0[(long)(b0 + g_row) * 2496 + (f + 1) * 64 + g_c8] = p.v;
    }
    __syncthreads();
  }

  // FM: per row r, (S_half0)^2+(S_half1)^2 - q, reduced over the 16 col-lanes
  #pragma unroll
  for (int r = 0; r < 4; ++r) {
    float v = accS[0][r] * accS[0][r] + accS[1][r] * accS[1][r] - q[r];
    v += __shfl_xor(v, 1, 64);
    v += __shfl_xor(v, 2, 64);
    v += __shfl_xor(v, 4, 64);
    v += __shfl_xor(v, 8, 64);
    if (c16 == 0) s_fm[nh * 32 + mt * 16 + quad * 4 + r] = v;
  }
  // first-order term: 8 threads per row, fields strided by 8
  {
    int row = tid >> 3, fi = tid & 7;
    float lv = 0.f;
    for (int f = fi; f < NF; f += 8)
      lv += lin_table[(int)s_x[row * NF + f] + f * FD];
    lv += __shfl_xor(lv, 1, 64);
    lv += __shfl_xor(lv, 2, 64);
    lv += __shfl_xor(lv, 4, 64);
    if (fi == 0) s_lin[row] = lv;
  }
  __syncthreads();
  if (tid < 32)
    base[b0 + tid] = s_lin[tid] + lin_bias[0]
                   + 0.5f * (s_fm[tid] + s_fm[32 + tid]);
}

// ---------------------------------------------------------------------------
// MLP GEMM, m97-style: global_load_lds(16B) staging, XOR-swizzled unpadded
// LDS, tile 128x112xBK64 (4 n-blocks: 20% less A re-read than 80x5, and
// grid 512 = exactly 2 blocks/CU, no 2.5/CU tail).  C = relu((A@B + b)*
// BN_INV*g + be); cols >=400 written 0 (pad for next layer's 64-wide K).
// B staged with the round-0 explicit pattern: 3 unconditional + 1 guarded.
// ---------------------------------------------------------------------------
__global__ __launch_bounds__(256) void k_gemm(
    const u16* __restrict__ A, int lda, const u16* __restrict__ Bt, int ldb,
    int kit, const float* __restrict__ bias, const float* __restrict__ g,
    const float* __restrict__ be, u16* __restrict__ C, int ldc)
{
  __shared__ __align__(16) u16 sA[128 * 64];  // 16 KB, chunk-swizzled
  __shared__ __align__(16) u16 sB[112 * 64];  // 14 KB

  const int tid = threadIdx.x;
  // 512 blocks = 8 xcd * 16 m * 4 n : co-locate an A-panel's 4 n-blocks per XCD
  int bid = blockIdx.x;
  int xcd = bid & 7;
  int j = bid >> 3;
  const int m0 = (xcd * 16 + (j >> 2)) * 128;
  const int n0 = (j & 3) * 112;

  const int wave = tid >> 6, lane = tid & 63;
  const int quad = lane >> 4, c16 = lane & 15;

  const int srow = lane >> 3;
  const int sclog = (lane & 7) ^ (srow & 7);
  const u16* gA = A + (long)m0 * lda + sclog * 8;
  const u16* gB = Bt + (long)n0 * ldb + sclog * 8;

  f32x4 acc[2][7];
  #pragma unroll
  for (int mtt = 0; mtt < 2; ++mtt)
    #pragma unroll
    for (int nt = 0; nt < 7; ++nt) acc[mtt][nt] = {0.f, 0.f, 0.f, 0.f};

  for (int kk = 0; kk < kit; ++kk) {
    const int k0 = kk * 64;
    #pragma unroll
    for (int it = 0; it < 4; ++it) {
      int s = wave * 4 + it;
      gld16(gA + (long)(s * 8 + srow) * lda + k0, &sA[s * 512]);
    }
    gld16(gB + (long)(wave * 8 + srow) * ldb + k0, &sB[wave * 512]);
    gld16(gB + (long)((wave + 4) * 8 + srow) * ldb + k0, &sB[(wave + 4) * 512]);
    gld16(gB + (long)((wave + 8) * 8 + srow) * ldb + k0, &sB[(wave + 8) * 512]);
    if (wave < 2)
      gld16(gB + (long)((wave + 12) * 8 + srow) * ldb + k0, &sB[(wave + 12) * 512]);
    __syncthreads();

    #pragma unroll
    for (int ks = 0; ks < 2; ++ks) {
      const int co = ((ks * 4 + quad) ^ (c16 & 7)) * 8;
      bf16x8 a0 = *(const bf16x8*)&sA[(wave * 32 + c16) * 64 + co];
      bf16x8 a1 = *(const bf16x8*)&sA[(wave * 32 + 16 + c16) * 64 + co];
      #pragma unroll
      for (int nt = 0; nt < 7; ++nt) {
        bf16x8 b = *(const bf16x8*)&sB[(nt * 16 + c16) * 64 + co];
        acc[0][nt] = __builtin_amdgcn_mfma_f32_16x16x32_bf16(a0, b, acc[0][nt], 0, 0, 0);
        acc[1][nt] = __builtin_amdgcn_mfma_f32_16x16x32_bf16(a1, b, acc[1][nt], 0, 0, 0);
      }
    }
    __syncthreads();
  }

  const float BN_INV = 0.9999950000374997f;
  #pragma unroll
  for (int nt = 0; nt < 7; ++nt) {
    int col = n0 + nt * 16 + c16;
    if (col < 400) {
      float bb = bias[col];
      float sc = BN_INV * g[col];
      float bv = be[col];
      #pragma unroll
      for (int mtt = 0; mtt < 2; ++mtt) {
        #pragma unroll
        for (int r = 0; r < 4; ++r) {
          int row = m0 + wave * 32 + mtt * 16 + quad * 4 + r;
          float y = (acc[mtt][nt][r] + bb) * sc + bv;
          y = fmaxf(y, 0.f);
          C[(long)row * ldc + col] = f2bf(y);
        }
      }
    } else if (col < ldc) {
      #pragma unroll
      for (int mtt = 0; mtt < 2; ++mtt)
        #pragma unroll
        for (int r = 0; r < 4; ++r)
          C[(long)(m0 + wave * 32 + mtt * 16 + quad * 4 + r) * ldc + col] = 0;
    }
  }
}

// ---------------------------------------------------------------------------
// Final: out[b] = sigmoid(base[b] + h3[b,:].Wout + bout). One wave per row.
// ---------------------------------------------------------------------------
__global__ __launch_bounds__(256) void k_final(
    const u16* __restrict__ h3, const float* __restrict__ Wout,
    const float* __restrict__ bout, const float* __restrict__ base,
    float* __restrict__ out)
{
  int wave = threadIdx.x >> 6, lane = threadIdx.x & 63;
  int b = blockIdx.x * 4 + wave;
  float s = 0.f;
  for (int jj = lane; jj < 400; jj += 64)
    s += bf2f(h3[(long)b * 448 + jj]) * Wout[jj];
  #pragma unroll
  for (int m = 32; m >= 1; m >>= 1) s += __shfl_xor(s, m, 64);
  if (lane == 0) {
    float z = s + base[b] + bout[0];
    out[b] = 1.0f / (1.0f + __expf(-z));
  }
}

extern "C" void kernel_launch(void* const* d_in, const int* in_sizes, int n_in,
                              void* d_out, int out_size, void* d_ws, size_t ws_size,
                              hipStream_t stream)
{
  const int*   x         = (const int*)d_in[0];
  const float* emb       = (const float*)d_in[1];
  const float* lin_table = (const float*)d_in[2];
  const float* lin_bias  = (const float*)d_in[3];
  const float* svar      = (const float*)d_in[4];
  const float* Wt        = (const float*)d_in[5];
  const float* bt        = (const float*)d_in[6];
  const float* W1  = (const float*)d_in[7];
  const float* b1  = (const float*)d_in[8];
  const float* g1  = (const float*)d_in[9];
  const float* be1 = (const float*)d_in[10];
  const float* W2  = (const float*)d_in[11];
  const float* b2  = (const float*)d_in[12];
  const float* g2  = (const float*)d_in[13];
  const float* be2 = (const float*)d_in[14];
  const float* W3  = (const float*)d_in[15];
  const float* b3  = (const float*)d_in[16];
  const float* g3  = (const float*)d_in[17];
  const float* be3 = (const float*)d_in[18];
  const float* Wo  = (const float*)d_in[19];
  const float* bo  = (const float*)d_in[20];

  char* ws = (char*)d_ws;
  size_t off = 0;
  u16* h0 = (u16*)(ws + off);     off += (size_t)BT * 2496 * 2;   // 81.8 MB
  u16* h1 = (u16*)(ws + off);     off += (size_t)BT * 448 * 2;
  u16* h2 = (u16*)(ws + off);     off += (size_t)BT * 448 * 2;
  u16* h3 = (u16*)(ws + off);     off += (size_t)BT * 448 * 2;
  float* base = (float*)(ws + off); off += (size_t)BT * 4;
  u16* W1T = (u16*)(ws + off);    off += (size_t)448 * 2496 * 2;
  u16* W2T = (u16*)(ws + off);    off += (size_t)448 * 448 * 2;
  u16* W3T = (u16*)(ws + off);    off += (size_t)448 * 448 * 2;
  u16* Wtb = (u16*)(ws + off);    off += (size_t)NF * 4096 * 2;
  (void)ws_size; (void)in_sizes; (void)n_in; (void)out_size;

  k_prep<<<dim3(14, 78, 4), 256, 0, stream>>>(W1, W1T, W2, W2T, W3, W3T, Wt, Wtb);
  k_embed<<<512, 256, 0, stream>>>(x, emb, lin_table, lin_bias, svar, Wtb, bt,
                                   h0, base);
  k_gemm<<<512, 256, 0, stream>>>(h0, 2496, W1T, 2496, 39, b1, g1, be1, h1, 448);
  k_gemm<<<512, 256, 0, stream>>>(h1, 448, W2T, 448, 7, b2, g2, be2, h2, 448);
  k_gemm<<<512, 256, 0, stream>>>(h2, 448, W3T, 448, 7, b3, g3, be3, h3, 448);
  k_final<<<4096, 256, 0, stream>>>(h3, Wo, bo, base, (float*)d_out);
}